// Round 4
// baseline (1263.830 us; speedup 1.0000x reference)
//
#include <hip/hip_runtime.h>
#include <hip/hip_bf16.h>

#define NNODE 8256
#define NEDGE 132096
#define DD 32
#define HIDN 128
#define NGR 32
#define PERG 258
#define KPG (PERG*DD)    // 8256
#define KTOT 4096        // contraction K = HIDN*DD
#define BC 3             // centers per gather block (8256 = 3*2752)
#define CHUNK 32         // edges staged per LDS round
#define CC 16            // centers per contract block (8256 = 16*516)

typedef unsigned short ushortT;

__device__ __forceinline__ unsigned pk_bf16(float a, float b) {
    unsigned ua = __float_as_uint(a), ub = __float_as_uint(b);
    ua = (ua + 0x7fffu + ((ua >> 16) & 1u)) >> 16;
    ub = (ub + 0x7fffu + ((ub >> 16) & 1u)) >> 16;
    return ua | (ub << 16);
}
__device__ __forceinline__ float bf_lo(unsigned u) { return __uint_as_float(u << 16); }
__device__ __forceinline__ float bf_hi(unsigned u) { return __uint_as_float(u & 0xffff0000u); }

// ---------------- node encoders: h[N][32] ----------------
__global__ __launch_bounds__(256) void k_encode(
    const float* __restrict__ pos, const float* __restrict__ vel,
    const float* __restrict__ nw1, const float* __restrict__ nb1,
    const float* __restrict__ nw2, const float* __restrict__ nb2,
    const float* __restrict__ vw1, const float* __restrict__ vb1,
    const float* __restrict__ vw2, const float* __restrict__ vb2,
    float* __restrict__ h)
{
    int i = blockIdx.x * 256 + threadIdx.x;
    if (i >= NNODE) return;
    float p0 = pos[i*3], p1 = pos[i*3+1], p2 = pos[i*3+2];
    float v0 = vel[i*3], v1 = vel[i*3+1], v2 = vel[i*3+2];
    float accP[16], accV[16];
    #pragma unroll
    for (int f = 0; f < 16; f++) { accP[f] = nb2[f]; accV[f] = vb2[f]; }
    for (int j = 0; j < HIDN; j++) {
        float hp = p0*nw1[j] + p1*nw1[128+j] + p2*nw1[256+j] + nb1[j];
        hp = hp >= 0.f ? hp : 0.2f*hp;
        float hv = v0*vw1[j] + v1*vw1[128+j] + v2*vw1[256+j] + vb1[j];
        hv = hv >= 0.f ? hv : 0.2f*hv;
        #pragma unroll
        for (int f = 0; f < 16; f++) {
            accP[f] += hp * nw2[j*16+f];
            accV[f] += hv * vw2[j*16+f];
        }
    }
    #pragma unroll
    for (int f = 0; f < 16; f++) {
        h[(size_t)i*DD + f]      = accP[f];
        h[(size_t)i*DD + 16 + f] = accV[f];
    }
}

// ---------------- per-edge dist, max-dist, degree count ----------------
__global__ __launch_bounds__(256) void k_edge1(
    const float* __restrict__ pos, const int* __restrict__ ei,
    float* __restrict__ dist, unsigned* __restrict__ maxd, int* __restrict__ deg)
{
    int e = blockIdx.x * 256 + threadIdx.x;
    float dd = 0.f;
    if (e < NEDGE) {
        int c = ei[e], n = ei[NEDGE + e];
        float dx = pos[c*3]   - pos[n*3];
        float dy = pos[c*3+1] - pos[n*3+1];
        float dz = pos[c*3+2] - pos[n*3+2];
        dd = sqrtf(dx*dx + dy*dy + dz*dz);
        dist[e] = dd;
        atomicAdd(&deg[c], 1);
    }
    #pragma unroll
    for (int o = 32; o > 0; o >>= 1) dd = fmaxf(dd, __shfl_down(dd, o, 64));
    if ((threadIdx.x & 63) == 0) atomicMax(maxd, __float_as_uint(dd));
}

// ---------------- exclusive scan of degrees -> CSR offsets ----------------
__global__ __launch_bounds__(1024) void k_scan(const int* __restrict__ deg, int* __restrict__ off)
{
    __shared__ int s[1024];
    int t = threadIdx.x;
    int base = t * 9;
    int loc[9]; int sum = 0;
    #pragma unroll
    for (int k = 0; k < 9; k++) {
        int i = base + k;
        int v = (i < NNODE) ? deg[i] : 0;
        loc[k] = sum; sum += v;
    }
    s[t] = sum; __syncthreads();
    for (int o = 1; o < 1024; o <<= 1) {
        int v = (t >= o) ? s[t - o] : 0;
        __syncthreads();
        s[t] += v;
        __syncthreads();
    }
    int pre = (t == 0) ? 0 : s[t-1];
    #pragma unroll
    for (int k = 0; k < 9; k++) {
        int i = base + k;
        if (i < NNODE) off[i] = pre + loc[k];
    }
    if (t == 1023) off[NNODE] = s[1023];
}

// ---------------- scatter edges into CSR order ----------------
__global__ __launch_bounds__(256) void k_scatter(
    const int* __restrict__ ei, const int* __restrict__ off,
    int* __restrict__ cursor, int* __restrict__ sN, int* __restrict__ sE)
{
    int e = blockIdx.x * 256 + threadIdx.x;
    if (e >= NEDGE) return;
    int c = ei[e];
    int p = off[c] + atomicAdd(&cursor[c], 1);
    sN[p] = ei[NEDGE + e];
    sE[p] = e;
}

// ---------------- z2 (bf16, CSR slot order) ----------------
__global__ __launch_bounds__(256) void k_z2(
    const float* __restrict__ dist, const unsigned* __restrict__ maxdb,
    const int* __restrict__ sE,
    const float* __restrict__ w1, const float* __restrict__ b1,
    const float* __restrict__ w2, const float* __restrict__ b2,
    ushortT* __restrict__ z2o)
{
    __shared__ float z1s[4][8][HIDN];   // 16 KB
    int t = threadIdx.x;
    int wv = t >> 6, ln = t & 63;
    long i0 = ((long)blockIdx.x * 4 + wv) * 8;
    float inv = 3.14159265358979323846f / __uint_as_float(*maxdb);
    float w[8];
    #pragma unroll
    for (int c = 0; c < 8; c++) {
        int e = sE[i0 + c];
        w[c] = 0.5f * (cosf(dist[e] * inv) + 1.0f);
    }
    // phase A: z1[c][j] once per wave-batch
    int j0 = ln * 2;
    float2 w1v = *(const float2*)&w1[j0];
    float2 b1v = *(const float2*)&b1[j0];
    #pragma unroll
    for (int c = 0; c < 8; c++) {
        float2 z;
        z.x = fmaxf(w[c]*w1v.x + b1v.x, 0.f);
        z.y = fmaxf(w[c]*w1v.y + b1v.y, 0.f);
        *(float2*)&z1s[wv][c][j0] = z;
    }
    __syncthreads();
    // phase B: z2[col] = relu(sum_j z1[j]*w2[j][col] + b2)
    float2 acc[8];
    #pragma unroll
    for (int c = 0; c < 8; c++) acc[c] = make_float2(0.f, 0.f);
    #pragma unroll 2
    for (int j = 0; j < HIDN; j += 2) {
        float2 wa = *(const float2*)&w2[(j+0)*HIDN + j0];
        float2 wb = *(const float2*)&w2[(j+1)*HIDN + j0];
        #pragma unroll
        for (int c = 0; c < 8; c++) {
            float2 z = *(const float2*)&z1s[wv][c][j];
            acc[c].x += z.x*wa.x + z.y*wb.x;
            acc[c].y += z.x*wa.y + z.y*wb.y;
        }
    }
    float ba = b2[j0], bb = b2[j0+1];
    #pragma unroll
    for (int c = 0; c < 8; c++) {
        float ox = fmaxf(acc[c].x + ba, 0.f);
        float oy = fmaxf(acc[c].y + bb, 0.f);
        *(unsigned*)&z2o[(size_t)(i0 + c)*HIDN + j0] = pk_bf16(ox, oy);
    }
}

// ---------------- BN column stats ----------------
__global__ __launch_bounds__(256) void k_bnstats(const float* __restrict__ h, float* __restrict__ stats)
{
    int t = threadIdx.x;
    float s = 0.f, ss = 0.f;
    for (size_t i = (size_t)blockIdx.x*256 + t; i < (size_t)NNODE*DD; i += (size_t)gridDim.x*256) {
        float v = h[i]; s += v; ss += v*v;
    }
    __shared__ float r0[256], r1[256];
    r0[t] = s; r1[t] = ss;
    __syncthreads();
    if (t < 32) {
        float a = 0.f, b = 0.f;
        for (int k = t; k < 256; k += 32) { a += r0[k]; b += r1[k]; }
        atomicAdd(&stats[t], a);
        atomicAdd(&stats[32 + t], b);
    }
}

// ---------------- gather: G[node][4096] (bf16) = sum_e z2[e] (x) hn[n_e], /denom ----------------
// thread (hp=t>>2, dq=t&3): h rows {2hp, 2hp+1}, d cols [dq*8, dq*8+8)
__global__ __launch_bounds__(256, 4) void k_gather(
    const float* __restrict__ hin,
    const ushortT* __restrict__ z2, const int* __restrict__ off,
    const int* __restrict__ sN,
    const float* __restrict__ stats,
    const float* __restrict__ bng, const float* __restrict__ bnb,
    ushortT* __restrict__ Gbuf, float* __restrict__ hsum)
{
    __shared__ float s_scale[DD], s_shift[DD];
    __shared__ float s_sum[BC][DD];
    __shared__ __align__(16) float sHn[CHUNK*DD];   // 4 KB

    int t = threadIdx.x;
    if (t < DD) {
        float mu  = stats[t] * (1.0f/(float)NNODE);
        float var = stats[DD+t] * (1.0f/(float)NNODE) - mu*mu;
        float scv = rsqrtf(var + 1e-5f) * bng[t];
        s_scale[t] = scv;
        s_shift[t] = bnb[t] - mu*scv;
    }
    if (t < BC*DD) ((float*)s_sum)[t] = 0.f;
    __syncthreads();

    int blockBase = blockIdx.x * BC;
    int o0 = off[blockBase], o1 = off[blockBase+1], o2 = off[blockBase+2], o3 = off[blockBase+3];

    int h0 = (t >> 2) * 2;      // h rows h0, h0+1
    int d0 = (t & 3) * 8;       // d cols d0..d0+7
    int se = t >> 3;            // staging edge slot
    int sq = t & 7;             // staging quarter
    float4 sc4 = *(const float4*)&s_scale[sq*4];
    float4 sf4 = *(const float4*)&s_shift[sq*4];

    float g0[16], g1[16], g2[16];
    #pragma unroll
    for (int j = 0; j < 16; j++) { g0[j]=0.f; g1[j]=0.f; g2[j]=0.f; }

    #define EDGE_FMA(G, k) { \
        unsigned zz = *(const unsigned*)&z2[(size_t)(k)*HIDN + h0]; \
        float z0 = bf_lo(zz), z1 = bf_hi(zz); \
        const float4* hp_ = (const float4*)&sHn[((k) - base)*DD + d0]; \
        float4 xa = hp_[0], xb = hp_[1]; \
        G[0]+=z0*xa.x; G[1]+=z0*xa.y; G[2]+=z0*xa.z; G[3]+=z0*xa.w; \
        G[4]+=z0*xb.x; G[5]+=z0*xb.y; G[6]+=z0*xb.z; G[7]+=z0*xb.w; \
        G[8]+=z1*xa.x; G[9]+=z1*xa.y; G[10]+=z1*xa.z; G[11]+=z1*xa.w; \
        G[12]+=z1*xb.x; G[13]+=z1*xb.y; G[14]+=z1*xb.z; G[15]+=z1*xb.w; }
    #define CENTER_LOOP(G, LO, HI) { \
        int k_ = (LO); \
        for (; k_ + 4 <= (HI); k_ += 4) { \
            EDGE_FMA(G, k_); EDGE_FMA(G, k_+1); EDGE_FMA(G, k_+2); EDGE_FMA(G, k_+3); } \
        for (; k_ < (HI); ++k_) { EDGE_FMA(G, k_); } }

    for (int base = o0; base < o3; base += CHUNK) {
        int nE = min(CHUNK, o3 - base);
        if (se < nE) {
            int i = base + se;
            int n = sN[i];
            float4 x = *(const float4*)&hin[(size_t)n*DD + sq*4];
            x.x = x.x*sc4.x + sf4.x; x.y = x.y*sc4.y + sf4.y;
            x.z = x.z*sc4.z + sf4.z; x.w = x.w*sc4.w + sf4.w;
            *(float4*)&sHn[se*DD + sq*4] = x;
            int c = (i >= o1) + (i >= o2);
            atomicAdd(&s_sum[c][sq*4+0], x.x);
            atomicAdd(&s_sum[c][sq*4+1], x.y);
            atomicAdd(&s_sum[c][sq*4+2], x.z);
            atomicAdd(&s_sum[c][sq*4+3], x.w);
        }
        __syncthreads();
        int ce = base + nE;
        { int lo = base,          hi = min(ce, o1); CENTER_LOOP(g0, lo, hi); }
        { int lo = max(base, o1), hi = min(ce, o2); CENTER_LOOP(g1, lo, hi); }
        { int lo = max(base, o2), hi = ce;          CENTER_LOOP(g2, lo, hi); }
        __syncthreads();
    }
    #undef EDGE_FMA
    #undef CENTER_LOOP

    float id0 = 1.f / fmaxf((float)(o1-o0), 1.f);
    float id1 = 1.f / fmaxf((float)(o2-o1), 1.f);
    float id2 = 1.f / fmaxf((float)(o3-o2), 1.f);

    // write bf16 G: per center, rows h0/h0+1, 8 cols each (one uint4)
    #pragma unroll
    for (int i = 0; i < 2; i++) {
        size_t kbase = (size_t)(h0 + i) * DD + d0;
        const float* G[3] = { g0 + i*8, g1 + i*8, g2 + i*8 };
        float ids[3] = { id0, id1, id2 };
        #pragma unroll
        for (int c = 0; c < BC; c++) {
            uint4 o;
            o.x = pk_bf16(G[c][0]*ids[c], G[c][1]*ids[c]);
            o.y = pk_bf16(G[c][2]*ids[c], G[c][3]*ids[c]);
            o.z = pk_bf16(G[c][4]*ids[c], G[c][5]*ids[c]);
            o.w = pk_bf16(G[c][6]*ids[c], G[c][7]*ids[c]);
            *(uint4*)&Gbuf[(size_t)(blockBase + c)*KTOT + kbase] = o;
        }
    }
    if (t < BC*DD) {
        int c = t >> 5, f = t & 31;
        float idc = (c == 0) ? id0 : (c == 1) ? id1 : id2;
        hsum[(size_t)(blockBase + c)*DD + f] = s_sum[c][f] * idc;
    }
}

// ---------------- contract: out[c][f] = G[c][0:4096] @ w3flat[0:4096][f] + bias + res ----------------
// w3 flat [128][1024] == [k=h*32+d][32] row-major.
__global__ __launch_bounds__(256, 4) void k_contract(
    const ushortT* __restrict__ Gbuf, const float* __restrict__ w3,
    const float* __restrict__ hsum, const float* __restrict__ b3,
    const float* __restrict__ convb,
    const float* __restrict__ hin, float* __restrict__ hout)
{
    __shared__ __align__(16) float sg[4][1024];   // 16 KB: per-wave 4 centers x 256 k (f32)
    int t = threadIdx.x;
    int wv = t >> 6, ln = t & 63;
    int cl = ln >> 4;           // local center 0..3
    int q16 = ln & 15;
    int f2 = q16 * 2;           // 2 output features
    int c = blockIdx.x*CC + wv*4 + cl;
    float* mySg = sg[wv];
    int xw = cl * 8;            // XOR swizzle

    float acc0 = 0.f, acc1 = 0.f;
    for (int kc = 0; kc < 16; kc++) {
        const ushortT* gsrc = Gbuf + (size_t)c*KTOT + kc*256;
        #pragma unroll
        for (int m = 0; m < 2; m++) {
            int k8 = (q16 + m*16) * 8;
            uint4 u = *(const uint4*)&gsrc[k8];
            float4 A = make_float4(bf_lo(u.x), bf_hi(u.x), bf_lo(u.y), bf_hi(u.y));
            float4 B = make_float4(bf_lo(u.z), bf_hi(u.z), bf_lo(u.w), bf_hi(u.w));
            *(float4*)&mySg[cl*256 + ( k8      ^ xw)] = A;
            *(float4*)&mySg[cl*256 + ((k8 + 4) ^ xw)] = B;
        }
        __syncthreads();
        const float* w3k = w3 + (size_t)(kc*256)*DD + f2;
        #pragma unroll 4
        for (int kk = 0; kk < 256; kk += 4) {
            float4 g = *(const float4*)&mySg[cl*256 + (kk ^ xw)];
            float2 wa = *(const float2*)&w3k[(kk+0)*DD];
            float2 wb = *(const float2*)&w3k[(kk+1)*DD];
            float2 wc = *(const float2*)&w3k[(kk+2)*DD];
            float2 wd = *(const float2*)&w3k[(kk+3)*DD];
            acc0 += g.x*wa.x + g.y*wb.x + g.z*wc.x + g.w*wd.x;
            acc1 += g.x*wa.y + g.y*wb.y + g.z*wc.y + g.w*wd.y;
        }
        __syncthreads();
    }
    float b0 = 0.f, b1v = 0.f;
    const float* hs = hsum + (size_t)c*DD;
    #pragma unroll 8
    for (int d = 0; d < DD; d++) {
        float h = hs[d];
        float2 bb = *(const float2*)&b3[d*DD + f2];
        b0  += h*bb.x;
        b1v += h*bb.y;
    }
    float2 r;
    r.x = acc0 + b0  + convb[f2]   + hin[(size_t)c*DD + f2];
    r.y = acc1 + b1v + convb[f2+1] + hin[(size_t)c*DD + f2+1];
    *(float2*)&hout[(size_t)c*DD + f2] = r;
}

// ---------------- LayerNorm into hLN ----------------
__global__ __launch_bounds__(256) void k_ln(const float* __restrict__ h,
    const float* __restrict__ lng, const float* __restrict__ lnb, float* __restrict__ hLN)
{
    int i = blockIdx.x * 256 + threadIdx.x;
    if (i >= NNODE) return;
    const float4* hr = (const float4*)(h + (size_t)i*DD);
    float4 v[8];
    float mu = 0.f;
    #pragma unroll
    for (int q = 0; q < 8; q++) { v[q] = hr[q]; mu += v[q].x+v[q].y+v[q].z+v[q].w; }
    mu *= (1.f/32.f);
    float var = 0.f;
    #pragma unroll
    for (int q = 0; q < 8; q++) {
        float d0=v[q].x-mu, d1=v[q].y-mu, d2=v[q].z-mu, d3=v[q].w-mu;
        var += d0*d0 + d1*d1 + d2*d2 + d3*d3;
    }
    var *= (1.f/32.f);
    float rs = rsqrtf(var + 1e-5f);
    float4* o = (float4*)(hLN + (size_t)i*DD);
    #pragma unroll
    for (int q = 0; q < 8; q++) {
        float4 gq = ((const float4*)lng)[q];
        float4 bq = ((const float4*)lnb)[q];
        float4 r;
        r.x = (v[q].x-mu)*rs*gq.x + bq.x;
        r.y = (v[q].y-mu)*rs*gq.y + bq.y;
        r.z = (v[q].z-mu)*rs*gq.z + bq.z;
        r.w = (v[q].w-mu)*rs*gq.w + bq.w;
        o[q] = r;
    }
}

// ---------------- fc1 partial GEMV ----------------
__global__ __launch_bounds__(256) void k_fc1(const float* __restrict__ hLN,
    const float* __restrict__ w1, float* __restrict__ partial)
{
    int g = blockIdx.x >> 3, s = blockIdx.x & 7;
    int j = threadIdx.x & 127, half = threadIdx.x >> 7;
    int k0 = s*1032 + half*4;
    const float* x = hLN + (size_t)g*KPG;
    float a = 0.f;
    #pragma unroll 2
    for (int m = 0; m < 129; m++) {
        int k = k0 + m*8;
        float4 xv = *(const float4*)&x[k];
        const float* wp = w1 + (size_t)k*HIDN + j;
        a += xv.x * wp[0];
        a += xv.y * wp[HIDN];
        a += xv.z * wp[2*HIDN];
        a += xv.w * wp[3*HIDN];
    }
    partial[((size_t)blockIdx.x*2 + half)*HIDN + j] = a;
}

// ---------------- fc2 ----------------
__global__ __launch_bounds__(128) void k_fc2(const float* __restrict__ partial,
    const float* __restrict__ b1, const float* __restrict__ w2,
    const float* __restrict__ b2, float* __restrict__ out)
{
    __shared__ float hid[128];
    int g = blockIdx.x, t = threadIdx.x;
    float a = b1[t];
    #pragma unroll
    for (int p = 0; p < 16; p++) a += partial[(size_t)(g*16 + p)*HIDN + t];
    a = a >= 0.f ? a : 0.2f*a;
    hid[t] = a;
    __syncthreads();
    float o = b2[t];
    #pragma unroll 4
    for (int j = 0; j < 128; j++) o += hid[j]*w2[j*128 + t];
    out[(size_t)g*128 + t] = o;
}

extern "C" void kernel_launch(void* const* d_in, const int* in_sizes, int n_in,
                              void* d_out, int out_size, void* d_ws, size_t ws_size,
                              hipStream_t stream)
{
    const float* pos  = (const float*)d_in[0];
    const float* vel  = (const float*)d_in[1];
    const int*   eidx = (const int*)  d_in[2];
    const float* nw1 = (const float*)d_in[3];  const float* nb1 = (const float*)d_in[4];
    const float* nw2 = (const float*)d_in[5];  const float* nb2 = (const float*)d_in[6];
    const float* vw1 = (const float*)d_in[7];  const float* vb1 = (const float*)d_in[8];
    const float* vw2 = (const float*)d_in[9];  const float* vb2 = (const float*)d_in[10];
    const float* ew1 = (const float*)d_in[11]; const float* eb1 = (const float*)d_in[12];
    const float* ew2 = (const float*)d_in[13]; const float* eb2 = (const float*)d_in[14];
    const float* ew3 = (const float*)d_in[15]; const float* eb3 = (const float*)d_in[16];
    const float* cvb = (const float*)d_in[17];
    const float* b1g = (const float*)d_in[18]; const float* b1b = (const float*)d_in[19];
    const float* b2g = (const float*)d_in[20]; const float* b2b = (const float*)d_in[21];
    const float* lng = (const float*)d_in[22]; const float* lnb = (const float*)d_in[23];
    const float* fw1 = (const float*)d_in[24]; const float* fb1 = (const float*)d_in[25];
    const float* fw2 = (const float*)d_in[26]; const float* fb2 = (const float*)d_in[27];

    char* ws = (char*)d_ws;
    size_t off = 0;
    auto alloc = [&](size_t bytes) -> void* {
        void* p = ws + off;
        off = (off + bytes + 255) & ~(size_t)255;
        return p;
    };
    unsigned* maxd  = (unsigned*)alloc(4);
    float* stats1   = (float*)alloc(64*4);
    float* stats2   = (float*)alloc(64*4);
    int* deg        = (int*)alloc((size_t)NNODE*4);
    int* cursor     = (int*)alloc((size_t)NNODE*4);
    size_t zeroBytes = off;
    int* offs       = (int*)alloc((size_t)(NNODE+1)*4);
    int* sN         = (int*)alloc((size_t)NEDGE*4);
    int* sE         = (int*)alloc((size_t)NEDGE*4);
    float* dist     = (float*)alloc((size_t)NEDGE*4);
    float* hA       = (float*)alloc((size_t)NNODE*DD*4);
    float* hB       = (float*)alloc((size_t)NNODE*DD*4);
    float* hLN      = (float*)alloc((size_t)NNODE*DD*4);
    float* hsum     = (float*)alloc((size_t)NNODE*DD*4);
    float* partial  = (float*)alloc((size_t)NGR*16*HIDN*4);
    ushortT* Gbuf   = (ushortT*)alloc((size_t)NNODE*KTOT*2);   // 67.6 MB bf16
    ushortT* z2buf  = (ushortT*)alloc((size_t)NEDGE*HIDN*2);   // 33.8 MB bf16

    hipMemsetAsync(d_ws, 0, zeroBytes, stream);

    k_encode<<<(NNODE+255)/256, 256, 0, stream>>>(pos, vel, nw1, nb1, nw2, nb2,
                                                  vw1, vb1, vw2, vb2, hA);
    k_edge1<<<NEDGE/256, 256, 0, stream>>>(pos, eidx, dist, maxd, deg);
    k_scan<<<1, 1024, 0, stream>>>(deg, offs);
    k_scatter<<<NEDGE/256, 256, 0, stream>>>(eidx, offs, cursor, sN, sE);
    k_z2<<<NEDGE/32, 256, 0, stream>>>(dist, maxd, sE, ew1, eb1, ew2, eb2, z2buf);

    k_bnstats<<<64, 256, 0, stream>>>(hA, stats1);
    k_gather<<<NNODE/BC, 256, 0, stream>>>(hA, z2buf, offs, sN,
                                           stats1, b1g, b1b, Gbuf, hsum);
    k_contract<<<NNODE/CC, 256, 0, stream>>>(Gbuf, ew3, hsum, eb3, cvb, hA, hB);

    k_bnstats<<<64, 256, 0, stream>>>(hB, stats2);
    k_gather<<<NNODE/BC, 256, 0, stream>>>(hB, z2buf, offs, sN,
                                           stats2, b2g, b2b, Gbuf, hsum);
    k_contract<<<NNODE/CC, 256, 0, stream>>>(Gbuf, ew3, hsum, eb3, cvb, hB, hA);

    k_ln<<<(NNODE+255)/256, 256, 0, stream>>>(hA, lng, lnb, hLN);
    k_fc1<<<NGR*8, 256, 0, stream>>>(hLN, fw1, partial);
    k_fc2<<<NGR, 128, 0, stream>>>(partial, fb1, fw2, fb2, (float*)d_out);
}

// Round 5
// 605.471 us; speedup vs baseline: 2.0873x; 2.0873x over previous
//
#include <hip/hip_runtime.h>
#include <hip/hip_bf16.h>

#define NNODE 8256
#define NEDGE 132096
#define DD 32
#define HIDN 128
#define NGR 32
#define PERG 258
#define KPG (PERG*DD)    // 8256
#define KTOT 4096        // h*32+d
#define KTOT2 4128       // + 32 bias slots (hsum)
#define NSTEP 129        // K-steps of 32 over KTOT2
#define BC 3             // centers per gather block (8256 = 3*2752)
#define CHUNK 32         // edges staged per LDS round

typedef unsigned short ushortT;
typedef __attribute__((ext_vector_type(8))) short short8v;   // 8 bf16 (4 VGPRs)
typedef __attribute__((ext_vector_type(4))) float float4v;   // MFMA 16x16 accumulator

__device__ __forceinline__ unsigned pk_bf16(float a, float b) {
    unsigned ua = __float_as_uint(a), ub = __float_as_uint(b);
    ua = (ua + 0x7fffu + ((ua >> 16) & 1u)) >> 16;
    ub = (ub + 0x7fffu + ((ub >> 16) & 1u)) >> 16;
    return ua | (ub << 16);
}
__device__ __forceinline__ float bf_lo(unsigned u) { return __uint_as_float(u << 16); }
__device__ __forceinline__ float bf_hi(unsigned u) { return __uint_as_float(u & 0xffff0000u); }

// ---------------- node encoders: h[N][32] ----------------
__global__ __launch_bounds__(256) void k_encode(
    const float* __restrict__ pos, const float* __restrict__ vel,
    const float* __restrict__ nw1, const float* __restrict__ nb1,
    const float* __restrict__ nw2, const float* __restrict__ nb2,
    const float* __restrict__ vw1, const float* __restrict__ vb1,
    const float* __restrict__ vw2, const float* __restrict__ vb2,
    float* __restrict__ h)
{
    int i = blockIdx.x * 256 + threadIdx.x;
    if (i >= NNODE) return;
    float p0 = pos[i*3], p1 = pos[i*3+1], p2 = pos[i*3+2];
    float v0 = vel[i*3], v1 = vel[i*3+1], v2 = vel[i*3+2];
    float accP[16], accV[16];
    #pragma unroll
    for (int f = 0; f < 16; f++) { accP[f] = nb2[f]; accV[f] = vb2[f]; }
    for (int j = 0; j < HIDN; j++) {
        float hp = p0*nw1[j] + p1*nw1[128+j] + p2*nw1[256+j] + nb1[j];
        hp = hp >= 0.f ? hp : 0.2f*hp;
        float hv = v0*vw1[j] + v1*vw1[128+j] + v2*vw1[256+j] + vb1[j];
        hv = hv >= 0.f ? hv : 0.2f*hv;
        #pragma unroll
        for (int f = 0; f < 16; f++) {
            accP[f] += hp * nw2[j*16+f];
            accV[f] += hv * vw2[j*16+f];
        }
    }
    #pragma unroll
    for (int f = 0; f < 16; f++) {
        h[(size_t)i*DD + f]      = accP[f];
        h[(size_t)i*DD + 16 + f] = accV[f];
    }
}

// ---------------- per-edge dist, max-dist, degree count ----------------
__global__ __launch_bounds__(256) void k_edge1(
    const float* __restrict__ pos, const int* __restrict__ ei,
    float* __restrict__ dist, unsigned* __restrict__ maxd, int* __restrict__ deg)
{
    int e = blockIdx.x * 256 + threadIdx.x;
    float dd = 0.f;
    if (e < NEDGE) {
        int c = ei[e], n = ei[NEDGE + e];
        float dx = pos[c*3]   - pos[n*3];
        float dy = pos[c*3+1] - pos[n*3+1];
        float dz = pos[c*3+2] - pos[n*3+2];
        dd = sqrtf(dx*dx + dy*dy + dz*dz);
        dist[e] = dd;
        atomicAdd(&deg[c], 1);
    }
    #pragma unroll
    for (int o = 32; o > 0; o >>= 1) dd = fmaxf(dd, __shfl_down(dd, o, 64));
    if ((threadIdx.x & 63) == 0) atomicMax(maxd, __float_as_uint(dd));
}

// ---------------- exclusive scan of degrees -> CSR offsets ----------------
__global__ __launch_bounds__(1024) void k_scan(const int* __restrict__ deg, int* __restrict__ off)
{
    __shared__ int s[1024];
    int t = threadIdx.x;
    int base = t * 9;
    int loc[9]; int sum = 0;
    #pragma unroll
    for (int k = 0; k < 9; k++) {
        int i = base + k;
        int v = (i < NNODE) ? deg[i] : 0;
        loc[k] = sum; sum += v;
    }
    s[t] = sum; __syncthreads();
    for (int o = 1; o < 1024; o <<= 1) {
        int v = (t >= o) ? s[t - o] : 0;
        __syncthreads();
        s[t] += v;
        __syncthreads();
    }
    int pre = (t == 0) ? 0 : s[t-1];
    #pragma unroll
    for (int k = 0; k < 9; k++) {
        int i = base + k;
        if (i < NNODE) off[i] = pre + loc[k];
    }
    if (t == 1023) off[NNODE] = s[1023];
}

// ---------------- scatter edges into CSR order ----------------
__global__ __launch_bounds__(256) void k_scatter(
    const int* __restrict__ ei, const int* __restrict__ off,
    int* __restrict__ cursor, int* __restrict__ sN, int* __restrict__ sE)
{
    int e = blockIdx.x * 256 + threadIdx.x;
    if (e >= NEDGE) return;
    int c = ei[e];
    int p = off[c] + atomicAdd(&cursor[c], 1);
    sN[p] = ei[NEDGE + e];
    sE[p] = e;
}

// ---------------- z2 (bf16, CSR slot order) ----------------
__global__ __launch_bounds__(256) void k_z2(
    const float* __restrict__ dist, const unsigned* __restrict__ maxdb,
    const int* __restrict__ sE,
    const float* __restrict__ w1, const float* __restrict__ b1,
    const float* __restrict__ w2, const float* __restrict__ b2,
    ushortT* __restrict__ z2o)
{
    __shared__ float z1s[4][8][HIDN];   // 16 KB
    int t = threadIdx.x;
    int wv = t >> 6, ln = t & 63;
    long i0 = ((long)blockIdx.x * 4 + wv) * 8;
    float inv = 3.14159265358979323846f / __uint_as_float(*maxdb);
    float w[8];
    #pragma unroll
    for (int c = 0; c < 8; c++) {
        int e = sE[i0 + c];
        w[c] = 0.5f * (cosf(dist[e] * inv) + 1.0f);
    }
    int j0 = ln * 2;
    float2 w1v = *(const float2*)&w1[j0];
    float2 b1v = *(const float2*)&b1[j0];
    #pragma unroll
    for (int c = 0; c < 8; c++) {
        float2 z;
        z.x = fmaxf(w[c]*w1v.x + b1v.x, 0.f);
        z.y = fmaxf(w[c]*w1v.y + b1v.y, 0.f);
        *(float2*)&z1s[wv][c][j0] = z;
    }
    __syncthreads();
    float2 acc[8];
    #pragma unroll
    for (int c = 0; c < 8; c++) acc[c] = make_float2(0.f, 0.f);
    #pragma unroll 2
    for (int j = 0; j < HIDN; j += 2) {
        float2 wa = *(const float2*)&w2[(j+0)*HIDN + j0];
        float2 wb = *(const float2*)&w2[(j+1)*HIDN + j0];
        #pragma unroll
        for (int c = 0; c < 8; c++) {
            float2 z = *(const float2*)&z1s[wv][c][j];
            acc[c].x += z.x*wa.x + z.y*wb.x;
            acc[c].y += z.x*wa.y + z.y*wb.y;
        }
    }
    float ba = b2[j0], bb = b2[j0+1];
    #pragma unroll
    for (int c = 0; c < 8; c++) {
        float ox = fmaxf(acc[c].x + ba, 0.f);
        float oy = fmaxf(acc[c].y + bb, 0.f);
        *(unsigned*)&z2o[(size_t)(i0 + c)*HIDN + j0] = pk_bf16(ox, oy);
    }
}

// ---------------- BN column stats ----------------
__global__ __launch_bounds__(256) void k_bnstats(const float* __restrict__ h, float* __restrict__ stats)
{
    int t = threadIdx.x;
    float s = 0.f, ss = 0.f;
    for (size_t i = (size_t)blockIdx.x*256 + t; i < (size_t)NNODE*DD; i += (size_t)gridDim.x*256) {
        float v = h[i]; s += v; ss += v*v;
    }
    __shared__ float r0[256], r1[256];
    r0[t] = s; r1[t] = ss;
    __syncthreads();
    if (t < 32) {
        float a = 0.f, b = 0.f;
        for (int k = t; k < 256; k += 32) { a += r0[k]; b += r1[k]; }
        atomicAdd(&stats[t], a);
        atomicAdd(&stats[32 + t], b);
    }
}

// ---------------- gather: G[node][4128] (bf16) = [sum_e z2 (x) hn | hsum], /denom ----------------
__global__ __launch_bounds__(256, 4) void k_gather(
    const float* __restrict__ hin,
    const ushortT* __restrict__ z2, const int* __restrict__ off,
    const int* __restrict__ sN,
    const float* __restrict__ stats,
    const float* __restrict__ bng, const float* __restrict__ bnb,
    ushortT* __restrict__ Gbuf)
{
    __shared__ float s_scale[DD], s_shift[DD];
    __shared__ float s_sum[BC][DD];
    __shared__ __align__(16) float sHn[CHUNK*DD];   // 4 KB

    int t = threadIdx.x;
    if (t < DD) {
        float mu  = stats[t] * (1.0f/(float)NNODE);
        float var = stats[DD+t] * (1.0f/(float)NNODE) - mu*mu;
        float scv = rsqrtf(var + 1e-5f) * bng[t];
        s_scale[t] = scv;
        s_shift[t] = bnb[t] - mu*scv;
    }
    if (t < BC*DD) ((float*)s_sum)[t] = 0.f;
    __syncthreads();

    int blockBase = blockIdx.x * BC;
    int o0 = off[blockBase], o1 = off[blockBase+1], o2 = off[blockBase+2], o3 = off[blockBase+3];

    int h0 = (t >> 2) * 2;      // h rows h0, h0+1
    int d0 = (t & 3) * 8;       // d cols d0..d0+7
    int se = t >> 3;            // staging edge slot
    int sq = t & 7;             // staging quarter
    float4 sc4 = *(const float4*)&s_scale[sq*4];
    float4 sf4 = *(const float4*)&s_shift[sq*4];

    float g0[16], g1[16], g2[16];
    #pragma unroll
    for (int j = 0; j < 16; j++) { g0[j]=0.f; g1[j]=0.f; g2[j]=0.f; }

    #define EDGE_FMA(G, k) { \
        unsigned zz = *(const unsigned*)&z2[(size_t)(k)*HIDN + h0]; \
        float z0 = bf_lo(zz), z1 = bf_hi(zz); \
        const float4* hp_ = (const float4*)&sHn[((k) - base)*DD + d0]; \
        float4 xa = hp_[0], xb = hp_[1]; \
        G[0]+=z0*xa.x; G[1]+=z0*xa.y; G[2]+=z0*xa.z; G[3]+=z0*xa.w; \
        G[4]+=z0*xb.x; G[5]+=z0*xb.y; G[6]+=z0*xb.z; G[7]+=z0*xb.w; \
        G[8]+=z1*xa.x; G[9]+=z1*xa.y; G[10]+=z1*xa.z; G[11]+=z1*xa.w; \
        G[12]+=z1*xb.x; G[13]+=z1*xb.y; G[14]+=z1*xb.z; G[15]+=z1*xb.w; }
    #define CENTER_LOOP(G, LO, HI) { \
        int k_ = (LO); \
        for (; k_ + 4 <= (HI); k_ += 4) { \
            EDGE_FMA(G, k_); EDGE_FMA(G, k_+1); EDGE_FMA(G, k_+2); EDGE_FMA(G, k_+3); } \
        for (; k_ < (HI); ++k_) { EDGE_FMA(G, k_); } }

    for (int base = o0; base < o3; base += CHUNK) {
        int nE = min(CHUNK, o3 - base);
        if (se < nE) {
            int i = base + se;
            int n = sN[i];
            float4 x = *(const float4*)&hin[(size_t)n*DD + sq*4];
            x.x = x.x*sc4.x + sf4.x; x.y = x.y*sc4.y + sf4.y;
            x.z = x.z*sc4.z + sf4.z; x.w = x.w*sc4.w + sf4.w;
            *(float4*)&sHn[se*DD + sq*4] = x;
            int c = (i >= o1) + (i >= o2);
            atomicAdd(&s_sum[c][sq*4+0], x.x);
            atomicAdd(&s_sum[c][sq*4+1], x.y);
            atomicAdd(&s_sum[c][sq*4+2], x.z);
            atomicAdd(&s_sum[c][sq*4+3], x.w);
        }
        __syncthreads();
        int ce = base + nE;
        { int lo = base,          hi = min(ce, o1); CENTER_LOOP(g0, lo, hi); }
        { int lo = max(base, o1), hi = min(ce, o2); CENTER_LOOP(g1, lo, hi); }
        { int lo = max(base, o2), hi = ce;          CENTER_LOOP(g2, lo, hi); }
        __syncthreads();
    }
    #undef EDGE_FMA
    #undef CENTER_LOOP

    float id0 = 1.f / fmaxf((float)(o1-o0), 1.f);
    float id1 = 1.f / fmaxf((float)(o2-o1), 1.f);
    float id2 = 1.f / fmaxf((float)(o3-o2), 1.f);

    #pragma unroll
    for (int i = 0; i < 2; i++) {
        size_t kbase = (size_t)(h0 + i) * DD + d0;
        const float* G[3] = { g0 + i*8, g1 + i*8, g2 + i*8 };
        float ids[3] = { id0, id1, id2 };
        #pragma unroll
        for (int c = 0; c < BC; c++) {
            uint4 o;
            o.x = pk_bf16(G[c][0]*ids[c], G[c][1]*ids[c]);
            o.y = pk_bf16(G[c][2]*ids[c], G[c][3]*ids[c]);
            o.z = pk_bf16(G[c][4]*ids[c], G[c][5]*ids[c]);
            o.w = pk_bf16(G[c][6]*ids[c], G[c][7]*ids[c]);
            *(uint4*)&Gbuf[(size_t)(blockBase + c)*KTOT2 + kbase] = o;
        }
    }
    // bias K-slots: G[c][4096+d] = hsum[c][d]/denom
    if (t < BC*DD) {
        int c = t >> 5, f = t & 31;
        float idc = (c == 0) ? id0 : (c == 1) ? id1 : id2;
        float v = s_sum[c][f] * idc;
        Gbuf[(size_t)(blockBase + c)*KTOT2 + KTOT + f] = (ushortT)(pk_bf16(v, 0.f) & 0xffffu);
    }
}

// ---------------- pack B = [w3 ; b3] into MFMA fragment order (bf16) ----------------
// Bp[step][ntile][lane][8]: B[k = step*32 + 8*(lane>>4)+j][col = ntile*16 + (lane&15)]
__global__ __launch_bounds__(256) void k_packB(
    const float* __restrict__ w3, const float* __restrict__ b3, ushortT* __restrict__ Bp)
{
    int gid = blockIdx.x*256 + threadIdx.x;
    if (gid >= NSTEP*2*64) return;
    int step = gid >> 7;
    int ntile = (gid >> 6) & 1;
    int lane = gid & 63;
    int col = ntile*16 + (lane & 15);
    int kb = step*32 + 8*(lane >> 4);
    float v[8];
    #pragma unroll
    for (int j = 0; j < 8; j++) {
        int k = kb + j;
        v[j] = (k < KTOT) ? w3[(size_t)k*DD + col] : b3[(size_t)(k - KTOT)*DD + col];
    }
    uint4 o;
    o.x = pk_bf16(v[0], v[1]);
    o.y = pk_bf16(v[2], v[3]);
    o.z = pk_bf16(v[4], v[5]);
    o.w = pk_bf16(v[6], v[7]);
    *(uint4*)&Bp[(size_t)gid*8] = o;
}

// ---------------- contract via MFMA: C[8256x32] = G[8256x4128] @ B[4128x32] ----------------
__global__ __launch_bounds__(256) void k_contract(
    const ushortT* __restrict__ Gbuf, const ushortT* __restrict__ Bp,
    const float* __restrict__ convb,
    const float* __restrict__ hin, float* __restrict__ hout)
{
    __shared__ float sred[4][16][33];
    int t = threadIdx.x;
    int wv = t >> 6, ln = t & 63;
    int rowb = blockIdx.x * 16;
    int l16 = ln & 15, lh = ln >> 4;

    const ushortT* Arow = Gbuf + (size_t)(rowb + l16) * KTOT2 + lh * 8;

    float4v acc0 = {0.f,0.f,0.f,0.f}, acc1 = {0.f,0.f,0.f,0.f};
    for (int s = wv; s < NSTEP; s += 4) {
        short8v a  = *(const short8v*)(Arow + (size_t)s * 32);
        short8v b0 = *(const short8v*)(Bp + ((size_t)s*2 + 0)*512 + ln*8);
        short8v b1 = *(const short8v*)(Bp + ((size_t)s*2 + 1)*512 + ln*8);
        acc0 = __builtin_amdgcn_mfma_f32_16x16x32_bf16(a, b0, acc0, 0, 0, 0);
        acc1 = __builtin_amdgcn_mfma_f32_16x16x32_bf16(a, b1, acc1, 0, 0, 0);
    }
    #pragma unroll
    for (int r = 0; r < 4; r++) {
        int row = lh*4 + r;
        sred[wv][row][l16]      = acc0[r];
        sred[wv][row][16 + l16] = acc1[r];
    }
    __syncthreads();

    int row = t >> 4, c2 = (t & 15) * 2;
    float v0 = sred[0][row][c2]   + sred[1][row][c2]   + sred[2][row][c2]   + sred[3][row][c2];
    float v1 = sred[0][row][c2+1] + sred[1][row][c2+1] + sred[2][row][c2+1] + sred[3][row][c2+1];
    size_t o = (size_t)(rowb + row)*DD + c2;
    float2 res = *(const float2*)&hin[o];
    float2 r2;
    r2.x = v0 + convb[c2]   + res.x;
    r2.y = v1 + convb[c2+1] + res.y;
    *(float2*)&hout[o] = r2;
}

// ---------------- LayerNorm into hLN ----------------
__global__ __launch_bounds__(256) void k_ln(const float* __restrict__ h,
    const float* __restrict__ lng, const float* __restrict__ lnb, float* __restrict__ hLN)
{
    int i = blockIdx.x * 256 + threadIdx.x;
    if (i >= NNODE) return;
    const float4* hr = (const float4*)(h + (size_t)i*DD);
    float4 v[8];
    float mu = 0.f;
    #pragma unroll
    for (int q = 0; q < 8; q++) { v[q] = hr[q]; mu += v[q].x+v[q].y+v[q].z+v[q].w; }
    mu *= (1.f/32.f);
    float var = 0.f;
    #pragma unroll
    for (int q = 0; q < 8; q++) {
        float d0=v[q].x-mu, d1=v[q].y-mu, d2=v[q].z-mu, d3=v[q].w-mu;
        var += d0*d0 + d1*d1 + d2*d2 + d3*d3;
    }
    var *= (1.f/32.f);
    float rs = rsqrtf(var + 1e-5f);
    float4* o = (float4*)(hLN + (size_t)i*DD);
    #pragma unroll
    for (int q = 0; q < 8; q++) {
        float4 gq = ((const float4*)lng)[q];
        float4 bq = ((const float4*)lnb)[q];
        float4 r;
        r.x = (v[q].x-mu)*rs*gq.x + bq.x;
        r.y = (v[q].y-mu)*rs*gq.y + bq.y;
        r.z = (v[q].z-mu)*rs*gq.z + bq.z;
        r.w = (v[q].w-mu)*rs*gq.w + bq.w;
        o[q] = r;
    }
}

// ---------------- fc1 partial GEMV ----------------
__global__ __launch_bounds__(256) void k_fc1(const float* __restrict__ hLN,
    const float* __restrict__ w1, float* __restrict__ partial)
{
    int g = blockIdx.x >> 3, s = blockIdx.x & 7;
    int j = threadIdx.x & 127, half = threadIdx.x >> 7;
    int k0 = s*1032 + half*4;
    const float* x = hLN + (size_t)g*KPG;
    float a = 0.f;
    #pragma unroll 2
    for (int m = 0; m < 129; m++) {
        int k = k0 + m*8;
        float4 xv = *(const float4*)&x[k];
        const float* wp = w1 + (size_t)k*HIDN + j;
        a += xv.x * wp[0];
        a += xv.y * wp[HIDN];
        a += xv.z * wp[2*HIDN];
        a += xv.w * wp[3*HIDN];
    }
    partial[((size_t)blockIdx.x*2 + half)*HIDN + j] = a;
}

// ---------------- fc2 ----------------
__global__ __launch_bounds__(128) void k_fc2(const float* __restrict__ partial,
    const float* __restrict__ b1, const float* __restrict__ w2,
    const float* __restrict__ b2, float* __restrict__ out)
{
    __shared__ float hid[128];
    int g = blockIdx.x, t = threadIdx.x;
    float a = b1[t];
    #pragma unroll
    for (int p = 0; p < 16; p++) a += partial[(size_t)(g*16 + p)*HIDN + t];
    a = a >= 0.f ? a : 0.2f*a;
    hid[t] = a;
    __syncthreads();
    float o = b2[t];
    #pragma unroll 4
    for (int j = 0; j < 128; j++) o += hid[j]*w2[j*128 + t];
    out[(size_t)g*128 + t] = o;
}

extern "C" void kernel_launch(void* const* d_in, const int* in_sizes, int n_in,
                              void* d_out, int out_size, void* d_ws, size_t ws_size,
                              hipStream_t stream)
{
    const float* pos  = (const float*)d_in[0];
    const float* vel  = (const float*)d_in[1];
    const int*   eidx = (const int*)  d_in[2];
    const float* nw1 = (const float*)d_in[3];  const float* nb1 = (const float*)d_in[4];
    const float* nw2 = (const float*)d_in[5];  const float* nb2 = (const float*)d_in[6];
    const float* vw1 = (const float*)d_in[7];  const float* vb1 = (const float*)d_in[8];
    const float* vw2 = (const float*)d_in[9];  const float* vb2 = (const float*)d_in[10];
    const float* ew1 = (const float*)d_in[11]; const float* eb1 = (const float*)d_in[12];
    const float* ew2 = (const float*)d_in[13]; const float* eb2 = (const float*)d_in[14];
    const float* ew3 = (const float*)d_in[15]; const float* eb3 = (const float*)d_in[16];
    const float* cvb = (const float*)d_in[17];
    const float* b1g = (const float*)d_in[18]; const float* b1b = (const float*)d_in[19];
    const float* b2g = (const float*)d_in[20]; const float* b2b = (const float*)d_in[21];
    const float* lng = (const float*)d_in[22]; const float* lnb = (const float*)d_in[23];
    const float* fw1 = (const float*)d_in[24]; const float* fb1 = (const float*)d_in[25];
    const float* fw2 = (const float*)d_in[26]; const float* fb2 = (const float*)d_in[27];

    char* ws = (char*)d_ws;
    size_t off = 0;
    auto alloc = [&](size_t bytes) -> void* {
        void* p = ws + off;
        off = (off + bytes + 255) & ~(size_t)255;
        return p;
    };
    unsigned* maxd  = (unsigned*)alloc(4);
    float* stats1   = (float*)alloc(64*4);
    float* stats2   = (float*)alloc(64*4);
    int* deg        = (int*)alloc((size_t)NNODE*4);
    int* cursor     = (int*)alloc((size_t)NNODE*4);
    size_t zeroBytes = off;
    int* offs       = (int*)alloc((size_t)(NNODE+1)*4);
    int* sN         = (int*)alloc((size_t)NEDGE*4);
    int* sE         = (int*)alloc((size_t)NEDGE*4);
    float* dist     = (float*)alloc((size_t)NEDGE*4);
    float* hA       = (float*)alloc((size_t)NNODE*DD*4);
    float* hB       = (float*)alloc((size_t)NNODE*DD*4);
    float* hLN      = (float*)alloc((size_t)NNODE*DD*4);
    float* partial  = (float*)alloc((size_t)NGR*16*HIDN*4);
    ushortT* Bp     = (ushortT*)alloc((size_t)NSTEP*2*64*8*2);  // 264 KB
    ushortT* Gbuf   = (ushortT*)alloc((size_t)NNODE*KTOT2*2);   // 68.2 MB bf16
    ushortT* z2buf  = (ushortT*)alloc((size_t)NEDGE*HIDN*2);    // 33.8 MB bf16

    hipMemsetAsync(d_ws, 0, zeroBytes, stream);

    k_encode<<<(NNODE+255)/256, 256, 0, stream>>>(pos, vel, nw1, nb1, nw2, nb2,
                                                  vw1, vb1, vw2, vb2, hA);
    k_edge1<<<NEDGE/256, 256, 0, stream>>>(pos, eidx, dist, maxd, deg);
    k_scan<<<1, 1024, 0, stream>>>(deg, offs);
    k_scatter<<<NEDGE/256, 256, 0, stream>>>(eidx, offs, cursor, sN, sE);
    k_z2<<<NEDGE/32, 256, 0, stream>>>(dist, maxd, sE, ew1, eb1, ew2, eb2, z2buf);
    k_packB<<<(NSTEP*2*64 + 255)/256, 256, 0, stream>>>(ew3, eb3, Bp);

    k_bnstats<<<64, 256, 0, stream>>>(hA, stats1);
    k_gather<<<NNODE/BC, 256, 0, stream>>>(hA, z2buf, offs, sN,
                                           stats1, b1g, b1b, Gbuf);
    k_contract<<<NNODE/16, 256, 0, stream>>>(Gbuf, Bp, cvb, hA, hB);

    k_bnstats<<<64, 256, 0, stream>>>(hB, stats2);
    k_gather<<<NNODE/BC, 256, 0, stream>>>(hB, z2buf, offs, sN,
                                           stats2, b2g, b2b, Gbuf);
    k_contract<<<NNODE/16, 256, 0, stream>>>(Gbuf, Bp, cvb, hB, hA);

    k_ln<<<(NNODE+255)/256, 256, 0, stream>>>(hA, lng, lnb, hLN);
    k_fc1<<<NGR*8, 256, 0, stream>>>(hLN, fw1, partial);
    k_fc2<<<NGR, 128, 0, stream>>>(partial, fb1, fw2, fb2, (float*)d_out);
}

// Round 6
// 601.697 us; speedup vs baseline: 2.1004x; 1.0063x over previous
//
#include <hip/hip_runtime.h>
#include <hip/hip_bf16.h>

#define NNODE 8256
#define NEDGE 132096
#define DD 32
#define HIDN 128
#define NGR 32
#define PERG 258
#define KPG (PERG*DD)    // 8256
#define KTOT 4096        // h*32+d
#define KTOT2 4128       // + 32 bias slots (hsum)
#define NSTEP 129        // K-steps of 32 over KTOT2
#define BC 3             // centers per conv block (8256 = 3*2752)
#define CHUNK 32         // edges staged per LDS round
#define GROWB 8256       // bytes per center in sG (KTOT2*2)

typedef unsigned short ushortT;
typedef __attribute__((ext_vector_type(8))) short short8v;   // 8 bf16 (4 VGPRs)
typedef __attribute__((ext_vector_type(4))) float float4v;   // MFMA 16x16 accumulator

__device__ __forceinline__ unsigned pk_bf16(float a, float b) {
    unsigned ua = __float_as_uint(a), ub = __float_as_uint(b);
    ua = (ua + 0x7fffu + ((ua >> 16) & 1u)) >> 16;
    ub = (ub + 0x7fffu + ((ub >> 16) & 1u)) >> 16;
    return ua | (ub << 16);
}
__device__ __forceinline__ float bf_lo(unsigned u) { return __uint_as_float(u << 16); }
__device__ __forceinline__ float bf_hi(unsigned u) { return __uint_as_float(u & 0xffff0000u); }

// ---------------- node encoders: h[N][32] ----------------
__global__ __launch_bounds__(256) void k_encode(
    const float* __restrict__ pos, const float* __restrict__ vel,
    const float* __restrict__ nw1, const float* __restrict__ nb1,
    const float* __restrict__ nw2, const float* __restrict__ nb2,
    const float* __restrict__ vw1, const float* __restrict__ vb1,
    const float* __restrict__ vw2, const float* __restrict__ vb2,
    float* __restrict__ h)
{
    int i = blockIdx.x * 256 + threadIdx.x;
    if (i >= NNODE) return;
    float p0 = pos[i*3], p1 = pos[i*3+1], p2 = pos[i*3+2];
    float v0 = vel[i*3], v1 = vel[i*3+1], v2 = vel[i*3+2];
    float accP[16], accV[16];
    #pragma unroll
    for (int f = 0; f < 16; f++) { accP[f] = nb2[f]; accV[f] = vb2[f]; }
    for (int j = 0; j < HIDN; j++) {
        float hp = p0*nw1[j] + p1*nw1[128+j] + p2*nw1[256+j] + nb1[j];
        hp = hp >= 0.f ? hp : 0.2f*hp;
        float hv = v0*vw1[j] + v1*vw1[128+j] + v2*vw1[256+j] + vb1[j];
        hv = hv >= 0.f ? hv : 0.2f*hv;
        #pragma unroll
        for (int f = 0; f < 16; f++) {
            accP[f] += hp * nw2[j*16+f];
            accV[f] += hv * vw2[j*16+f];
        }
    }
    #pragma unroll
    for (int f = 0; f < 16; f++) {
        h[(size_t)i*DD + f]      = accP[f];
        h[(size_t)i*DD + 16 + f] = accV[f];
    }
}

// ---------------- per-edge dist, max-dist, degree count ----------------
__global__ __launch_bounds__(256) void k_edge1(
    const float* __restrict__ pos, const int* __restrict__ ei,
    float* __restrict__ dist, unsigned* __restrict__ maxd, int* __restrict__ deg)
{
    int e = blockIdx.x * 256 + threadIdx.x;
    float dd = 0.f;
    if (e < NEDGE) {
        int c = ei[e], n = ei[NEDGE + e];
        float dx = pos[c*3]   - pos[n*3];
        float dy = pos[c*3+1] - pos[n*3+1];
        float dz = pos[c*3+2] - pos[n*3+2];
        dd = sqrtf(dx*dx + dy*dy + dz*dz);
        dist[e] = dd;
        atomicAdd(&deg[c], 1);
    }
    #pragma unroll
    for (int o = 32; o > 0; o >>= 1) dd = fmaxf(dd, __shfl_down(dd, o, 64));
    if ((threadIdx.x & 63) == 0) atomicMax(maxd, __float_as_uint(dd));
}

// ---------------- exclusive scan of degrees -> CSR offsets ----------------
__global__ __launch_bounds__(1024) void k_scan(const int* __restrict__ deg, int* __restrict__ off)
{
    __shared__ int s[1024];
    int t = threadIdx.x;
    int base = t * 9;
    int loc[9]; int sum = 0;
    #pragma unroll
    for (int k = 0; k < 9; k++) {
        int i = base + k;
        int v = (i < NNODE) ? deg[i] : 0;
        loc[k] = sum; sum += v;
    }
    s[t] = sum; __syncthreads();
    for (int o = 1; o < 1024; o <<= 1) {
        int v = (t >= o) ? s[t - o] : 0;
        __syncthreads();
        s[t] += v;
        __syncthreads();
    }
    int pre = (t == 0) ? 0 : s[t-1];
    #pragma unroll
    for (int k = 0; k < 9; k++) {
        int i = base + k;
        if (i < NNODE) off[i] = pre + loc[k];
    }
    if (t == 1023) off[NNODE] = s[1023];
}

// ---------------- scatter edges into CSR order ----------------
__global__ __launch_bounds__(256) void k_scatter(
    const int* __restrict__ ei, const int* __restrict__ off,
    int* __restrict__ cursor, int* __restrict__ sN, int* __restrict__ sE)
{
    int e = blockIdx.x * 256 + threadIdx.x;
    if (e >= NEDGE) return;
    int c = ei[e];
    int p = off[c] + atomicAdd(&cursor[c], 1);
    sN[p] = ei[NEDGE + e];
    sE[p] = e;
}

// ---------------- z2 (bf16, CSR slot order) ----------------
__global__ __launch_bounds__(256) void k_z2(
    const float* __restrict__ dist, const unsigned* __restrict__ maxdb,
    const int* __restrict__ sE,
    const float* __restrict__ w1, const float* __restrict__ b1,
    const float* __restrict__ w2, const float* __restrict__ b2,
    ushortT* __restrict__ z2o)
{
    __shared__ float z1s[4][8][HIDN];   // 16 KB
    int t = threadIdx.x;
    int wv = t >> 6, ln = t & 63;
    long i0 = ((long)blockIdx.x * 4 + wv) * 8;
    float inv = 3.14159265358979323846f / __uint_as_float(*maxdb);
    float w[8];
    #pragma unroll
    for (int c = 0; c < 8; c++) {
        int e = sE[i0 + c];
        w[c] = 0.5f * (cosf(dist[e] * inv) + 1.0f);
    }
    int j0 = ln * 2;
    float2 w1v = *(const float2*)&w1[j0];
    float2 b1v = *(const float2*)&b1[j0];
    #pragma unroll
    for (int c = 0; c < 8; c++) {
        float2 z;
        z.x = fmaxf(w[c]*w1v.x + b1v.x, 0.f);
        z.y = fmaxf(w[c]*w1v.y + b1v.y, 0.f);
        *(float2*)&z1s[wv][c][j0] = z;
    }
    __syncthreads();
    float2 acc[8];
    #pragma unroll
    for (int c = 0; c < 8; c++) acc[c] = make_float2(0.f, 0.f);
    #pragma unroll 2
    for (int j = 0; j < HIDN; j += 2) {
        float2 wa = *(const float2*)&w2[(j+0)*HIDN + j0];
        float2 wb = *(const float2*)&w2[(j+1)*HIDN + j0];
        #pragma unroll
        for (int c = 0; c < 8; c++) {
            float2 z = *(const float2*)&z1s[wv][c][j];
            acc[c].x += z.x*wa.x + z.y*wb.x;
            acc[c].y += z.x*wa.y + z.y*wb.y;
        }
    }
    float ba = b2[j0], bb = b2[j0+1];
    #pragma unroll
    for (int c = 0; c < 8; c++) {
        float ox = fmaxf(acc[c].x + ba, 0.f);
        float oy = fmaxf(acc[c].y + bb, 0.f);
        *(unsigned*)&z2o[(size_t)(i0 + c)*HIDN + j0] = pk_bf16(ox, oy);
    }
}

// ---------------- BN column stats ----------------
__global__ __launch_bounds__(256) void k_bnstats(const float* __restrict__ h, float* __restrict__ stats)
{
    int t = threadIdx.x;
    float s = 0.f, ss = 0.f;
    for (size_t i = (size_t)blockIdx.x*256 + t; i < (size_t)NNODE*DD; i += (size_t)gridDim.x*256) {
        float v = h[i]; s += v; ss += v*v;
    }
    __shared__ float r0[256], r1[256];
    r0[t] = s; r1[t] = ss;
    __syncthreads();
    if (t < 32) {
        float a = 0.f, b = 0.f;
        for (int k = t; k < 256; k += 32) { a += r0[k]; b += r1[k]; }
        atomicAdd(&stats[t], a);
        atomicAdd(&stats[32 + t], b);
    }
}

// ---------------- pack B = [w3 ; b3] into MFMA fragment order (bf16) ----------------
// Bp[step][ntile][lane][8]: B[k = step*32 + 8*(lane>>4)+j][col = ntile*16 + (lane&15)]
__global__ __launch_bounds__(256) void k_packB(
    const float* __restrict__ w3, const float* __restrict__ b3, ushortT* __restrict__ Bp)
{
    int gid = blockIdx.x*256 + threadIdx.x;
    if (gid >= NSTEP*2*64) return;
    int step = gid >> 7;
    int ntile = (gid >> 6) & 1;
    int lane = gid & 63;
    int col = ntile*16 + (lane & 15);
    int kb = step*32 + 8*(lane >> 4);
    float v[8];
    #pragma unroll
    for (int j = 0; j < 8; j++) {
        int k = kb + j;
        v[j] = (k < KTOT) ? w3[(size_t)k*DD + col] : b3[(size_t)(k - KTOT)*DD + col];
    }
    uint4 o;
    o.x = pk_bf16(v[0], v[1]);
    o.y = pk_bf16(v[2], v[3]);
    o.z = pk_bf16(v[4], v[5]);
    o.w = pk_bf16(v[6], v[7]);
    *(uint4*)&Bp[(size_t)gid*8] = o;
}

// ---------------- fused NNConv: gather into LDS(bf16) + MFMA contract ----------------
// sG byte layout per center c: addr = c*GROWB + ((h*64 + m*16) ^ ((h&14)<<3)), m = d-octet.
// Bias row h=128 (k=4096..4127) unswizzled. Bijective in [0, 8256) per center.
__global__ __launch_bounds__(256) void k_conv(
    const float* __restrict__ hin, float* __restrict__ hout,
    const ushortT* __restrict__ z2, const int* __restrict__ off,
    const int* __restrict__ sN,
    const float* __restrict__ stats,
    const float* __restrict__ bng, const float* __restrict__ bnb,
    const ushortT* __restrict__ Bp, const float* __restrict__ convb)
{
    __shared__ float s_scale[DD], s_shift[DD];
    __shared__ float s_sum[BC][DD];
    __shared__ __align__(16) float sHn[CHUNK*DD];        // 4 KB; reused as sred in phase 2
    __shared__ __align__(16) ushortT sG[BC*KTOT2];       // 24.8 KB bf16 (swizzled)

    int t = threadIdx.x;
    int wv = t >> 6, ln = t & 63;
    if (t < DD) {
        float mu  = stats[t] * (1.0f/(float)NNODE);
        float var = stats[DD+t] * (1.0f/(float)NNODE) - mu*mu;
        float scv = rsqrtf(var + 1e-5f) * bng[t];
        s_scale[t] = scv;
        s_shift[t] = bnb[t] - mu*scv;
    }
    if (t < BC*DD) ((float*)s_sum)[t] = 0.f;
    __syncthreads();

    int blockBase = blockIdx.x * BC;
    int o0 = off[blockBase], o1 = off[blockBase+1], o2 = off[blockBase+2], o3 = off[blockBase+3];

    int h0 = (t >> 2) * 2;      // h rows h0, h0+1
    int d0 = (t & 3) * 8;       // d cols d0..d0+7
    int se = t >> 3;            // staging edge slot
    int sq = t & 7;             // staging quarter
    float4 sc4 = *(const float4*)&s_scale[sq*4];
    float4 sf4 = *(const float4*)&s_shift[sq*4];

    float g0[16], g1[16], g2[16];
    #pragma unroll
    for (int j = 0; j < 16; j++) { g0[j]=0.f; g1[j]=0.f; g2[j]=0.f; }

    #define EDGE_FMA(G, k) { \
        unsigned zz = *(const unsigned*)&z2[(size_t)(k)*HIDN + h0]; \
        float z0 = bf_lo(zz), z1 = bf_hi(zz); \
        const float4* hp_ = (const float4*)&sHn[((k) - base)*DD + d0]; \
        float4 xa = hp_[0], xb = hp_[1]; \
        G[0]+=z0*xa.x; G[1]+=z0*xa.y; G[2]+=z0*xa.z; G[3]+=z0*xa.w; \
        G[4]+=z0*xb.x; G[5]+=z0*xb.y; G[6]+=z0*xb.z; G[7]+=z0*xb.w; \
        G[8]+=z1*xa.x; G[9]+=z1*xa.y; G[10]+=z1*xa.z; G[11]+=z1*xa.w; \
        G[12]+=z1*xb.x; G[13]+=z1*xb.y; G[14]+=z1*xb.z; G[15]+=z1*xb.w; }
    #define CENTER_LOOP(G, LO, HI) { \
        int k_ = (LO); \
        for (; k_ + 4 <= (HI); k_ += 4) { \
            EDGE_FMA(G, k_); EDGE_FMA(G, k_+1); EDGE_FMA(G, k_+2); EDGE_FMA(G, k_+3); } \
        for (; k_ < (HI); ++k_) { EDGE_FMA(G, k_); } }

    for (int base = o0; base < o3; base += CHUNK) {
        int nE = min(CHUNK, o3 - base);
        if (se < nE) {
            int i = base + se;
            int n = sN[i];
            float4 x = *(const float4*)&hin[(size_t)n*DD + sq*4];
            x.x = x.x*sc4.x + sf4.x; x.y = x.y*sc4.y + sf4.y;
            x.z = x.z*sc4.z + sf4.z; x.w = x.w*sc4.w + sf4.w;
            *(float4*)&sHn[se*DD + sq*4] = x;
            int c = (i >= o1) + (i >= o2);
            atomicAdd(&s_sum[c][sq*4+0], x.x);
            atomicAdd(&s_sum[c][sq*4+1], x.y);
            atomicAdd(&s_sum[c][sq*4+2], x.z);
            atomicAdd(&s_sum[c][sq*4+3], x.w);
        }
        __syncthreads();
        int ce = base + nE;
        { int lo = base,          hi = min(ce, o1); CENTER_LOOP(g0, lo, hi); }
        { int lo = max(base, o1), hi = min(ce, o2); CENTER_LOOP(g1, lo, hi); }
        { int lo = max(base, o2), hi = ce;          CENTER_LOOP(g2, lo, hi); }
        __syncthreads();
    }
    #undef EDGE_FMA
    #undef CENTER_LOOP

    float id0 = 1.f / fmaxf((float)(o1-o0), 1.f);
    float id1 = 1.f / fmaxf((float)(o2-o1), 1.f);
    float id2 = 1.f / fmaxf((float)(o3-o2), 1.f);

    // pack G -> swizzled LDS bf16
    {
        float ids[3] = { id0, id1, id2 };
        float* Gs[3] = { g0, g1, g2 };
        #pragma unroll
        for (int i = 0; i < 2; i++) {
            int h = h0 + i;
            unsigned rb = (unsigned)(h*64 + d0*2) ^ (unsigned)((h & 14) << 3);
            #pragma unroll
            for (int c = 0; c < BC; c++) {
                const float* G = Gs[c] + i*8;
                float idc = ids[c];
                uint4 o;
                o.x = pk_bf16(G[0]*idc, G[1]*idc);
                o.y = pk_bf16(G[2]*idc, G[3]*idc);
                o.z = pk_bf16(G[4]*idc, G[5]*idc);
                o.w = pk_bf16(G[6]*idc, G[7]*idc);
                *(uint4*)((char*)sG + c*GROWB + rb) = o;
            }
        }
    }
    // bias K-slots k=4096+f (row h=128, unswizzled)
    if (t < BC*DD) {
        int c = t >> 5, f = t & 31;
        float idc = (c == 0) ? id0 : (c == 1) ? id1 : id2;
        float v = s_sum[c][f] * idc;
        sG[c*KTOT2 + KTOT + f] = (ushortT)(pk_bf16(v, 0.f) & 0xffffu);
    }
    __syncthreads();

    // phase 2: MFMA over K, strided across waves
    int l16 = ln & 15, lh = ln >> 4;
    float4v acc0 = {0.f,0.f,0.f,0.f}, acc1 = {0.f,0.f,0.f,0.f};
    for (int s = wv; s < NSTEP; s += 4) {
        short8v a = {0,0,0,0,0,0,0,0};
        if (l16 < BC) {
            unsigned byte = (unsigned)(l16*GROWB) +
                            ((unsigned)(s*64 + lh*16) ^ (unsigned)((s & 14) << 3));
            a = *(const short8v*)((const char*)sG + byte);
        }
        short8v b0 = *(const short8v*)(Bp + ((size_t)s*2 + 0)*512 + ln*8);
        short8v b1 = *(const short8v*)(Bp + ((size_t)s*2 + 1)*512 + ln*8);
        acc0 = __builtin_amdgcn_mfma_f32_16x16x32_bf16(a, b0, acc0, 0, 0, 0);
        acc1 = __builtin_amdgcn_mfma_f32_16x16x32_bf16(a, b1, acc1, 0, 0, 0);
    }
    // C rows 0..2 live in lanes lh==0, regs r<3 (row = 4*lh + r), col = l16
    float* sred = sHn;   // [4 waves][3 centers][32 cols] = 384 floats
    #pragma unroll
    for (int r = 0; r < 4; r++) {
        int row = lh*4 + r;
        if (row < BC) {
            sred[(wv*BC + row)*DD + l16]      = acc0[r];
            sred[(wv*BC + row)*DD + 16 + l16] = acc1[r];
        }
    }
    __syncthreads();

    if (t < BC*DD) {
        int c = t >> 5, f = t & 31;
        float s = sred[(0*BC+c)*DD+f] + sred[(1*BC+c)*DD+f]
                + sred[(2*BC+c)*DD+f] + sred[(3*BC+c)*DD+f];
        int node = blockBase + c;
        hout[(size_t)node*DD + f] = s + convb[f] + hin[(size_t)node*DD + f];
    }
}

// ---------------- LayerNorm into hLN ----------------
__global__ __launch_bounds__(256) void k_ln(const float* __restrict__ h,
    const float* __restrict__ lng, const float* __restrict__ lnb, float* __restrict__ hLN)
{
    int i = blockIdx.x * 256 + threadIdx.x;
    if (i >= NNODE) return;
    const float4* hr = (const float4*)(h + (size_t)i*DD);
    float4 v[8];
    float mu = 0.f;
    #pragma unroll
    for (int q = 0; q < 8; q++) { v[q] = hr[q]; mu += v[q].x+v[q].y+v[q].z+v[q].w; }
    mu *= (1.f/32.f);
    float var = 0.f;
    #pragma unroll
    for (int q = 0; q < 8; q++) {
        float d0=v[q].x-mu, d1=v[q].y-mu, d2=v[q].z-mu, d3=v[q].w-mu;
        var += d0*d0 + d1*d1 + d2*d2 + d3*d3;
    }
    var *= (1.f/32.f);
    float rs = rsqrtf(var + 1e-5f);
    float4* o = (float4*)(hLN + (size_t)i*DD);
    #pragma unroll
    for (int q = 0; q < 8; q++) {
        float4 gq = ((const float4*)lng)[q];
        float4 bq = ((const float4*)lnb)[q];
        float4 r;
        r.x = (v[q].x-mu)*rs*gq.x + bq.x;
        r.y = (v[q].y-mu)*rs*gq.y + bq.y;
        r.z = (v[q].z-mu)*rs*gq.z + bq.z;
        r.w = (v[q].w-mu)*rs*gq.w + bq.w;
        o[q] = r;
    }
}

// ---------------- fc1 partial GEMV ----------------
__global__ __launch_bounds__(256) void k_fc1(const float* __restrict__ hLN,
    const float* __restrict__ w1, float* __restrict__ partial)
{
    int g = blockIdx.x >> 3, s = blockIdx.x & 7;
    int j = threadIdx.x & 127, half = threadIdx.x >> 7;
    int k0 = s*1032 + half*4;
    const float* x = hLN + (size_t)g*KPG;
    float a = 0.f;
    #pragma unroll 2
    for (int m = 0; m < 129; m++) {
        int k = k0 + m*8;
        float4 xv = *(const float4*)&x[k];
        const float* wp = w1 + (size_t)k*HIDN + j;
        a += xv.x * wp[0];
        a += xv.y * wp[HIDN];
        a += xv.z * wp[2*HIDN];
        a += xv.w * wp[3*HIDN];
    }
    partial[((size_t)blockIdx.x*2 + half)*HIDN + j] = a;
}

// ---------------- fc2 ----------------
__global__ __launch_bounds__(128) void k_fc2(const float* __restrict__ partial,
    const float* __restrict__ b1, const float* __restrict__ w2,
    const float* __restrict__ b2, float* __restrict__ out)
{
    __shared__ float hid[128];
    int g = blockIdx.x, t = threadIdx.x;
    float a = b1[t];
    #pragma unroll
    for (int p = 0; p < 16; p++) a += partial[(size_t)(g*16 + p)*HIDN + t];
    a = a >= 0.f ? a : 0.2f*a;
    hid[t] = a;
    __syncthreads();
    float o = b2[t];
    #pragma unroll 4
    for (int j = 0; j < 128; j++) o += hid[j]*w2[j*128 + t];
    out[(size_t)g*128 + t] = o;
}

extern "C" void kernel_launch(void* const* d_in, const int* in_sizes, int n_in,
                              void* d_out, int out_size, void* d_ws, size_t ws_size,
                              hipStream_t stream)
{
    const float* pos  = (const float*)d_in[0];
    const float* vel  = (const float*)d_in[1];
    const int*   eidx = (const int*)  d_in[2];
    const float* nw1 = (const float*)d_in[3];  const float* nb1 = (const float*)d_in[4];
    const float* nw2 = (const float*)d_in[5];  const float* nb2 = (const float*)d_in[6];
    const float* vw1 = (const float*)d_in[7];  const float* vb1 = (const float*)d_in[8];
    const float* vw2 = (const float*)d_in[9];  const float* vb2 = (const float*)d_in[10];
    const float* ew1 = (const float*)d_in[11]; const float* eb1 = (const float*)d_in[12];
    const float* ew2 = (const float*)d_in[13]; const float* eb2 = (const float*)d_in[14];
    const float* ew3 = (const float*)d_in[15]; const float* eb3 = (const float*)d_in[16];
    const float* cvb = (const float*)d_in[17];
    const float* b1g = (const float*)d_in[18]; const float* b1b = (const float*)d_in[19];
    const float* b2g = (const float*)d_in[20]; const float* b2b = (const float*)d_in[21];
    const float* lng = (const float*)d_in[22]; const float* lnb = (const float*)d_in[23];
    const float* fw1 = (const float*)d_in[24]; const float* fb1 = (const float*)d_in[25];
    const float* fw2 = (const float*)d_in[26]; const float* fb2 = (const float*)d_in[27];

    char* ws = (char*)d_ws;
    size_t off = 0;
    auto alloc = [&](size_t bytes) -> void* {
        void* p = ws + off;
        off = (off + bytes + 255) & ~(size_t)255;
        return p;
    };
    unsigned* maxd  = (unsigned*)alloc(4);
    float* stats1   = (float*)alloc(64*4);
    float* stats2   = (float*)alloc(64*4);
    int* deg        = (int*)alloc((size_t)NNODE*4);
    int* cursor     = (int*)alloc((size_t)NNODE*4);
    size_t zeroBytes = off;
    int* offs       = (int*)alloc((size_t)(NNODE+1)*4);
    int* sN         = (int*)alloc((size_t)NEDGE*4);
    int* sE         = (int*)alloc((size_t)NEDGE*4);
    float* dist     = (float*)alloc((size_t)NEDGE*4);
    float* hA       = (float*)alloc((size_t)NNODE*DD*4);
    float* hB       = (float*)alloc((size_t)NNODE*DD*4);
    float* hLN      = (float*)alloc((size_t)NNODE*DD*4);
    float* partial  = (float*)alloc((size_t)NGR*16*HIDN*4);
    ushortT* Bp     = (ushortT*)alloc((size_t)NSTEP*2*64*8*2);  // 264 KB
    ushortT* z2buf  = (ushortT*)alloc((size_t)NEDGE*HIDN*2);    // 33.8 MB bf16

    hipMemsetAsync(d_ws, 0, zeroBytes, stream);

    k_encode<<<(NNODE+255)/256, 256, 0, stream>>>(pos, vel, nw1, nb1, nw2, nb2,
                                                  vw1, vb1, vw2, vb2, hA);
    k_edge1<<<NEDGE/256, 256, 0, stream>>>(pos, eidx, dist, maxd, deg);
    k_scan<<<1, 1024, 0, stream>>>(deg, offs);
    k_scatter<<<NEDGE/256, 256, 0, stream>>>(eidx, offs, cursor, sN, sE);
    k_z2<<<NEDGE/32, 256, 0, stream>>>(dist, maxd, sE, ew1, eb1, ew2, eb2, z2buf);
    k_packB<<<(NSTEP*2*64 + 255)/256, 256, 0, stream>>>(ew3, eb3, Bp);

    k_bnstats<<<64, 256, 0, stream>>>(hA, stats1);
    k_conv<<<NNODE/BC, 256, 0, stream>>>(hA, hB, z2buf, offs, sN,
                                         stats1, b1g, b1b, Bp, cvb);
    k_bnstats<<<64, 256, 0, stream>>>(hB, stats2);
    k_conv<<<NNODE/BC, 256, 0, stream>>>(hB, hA, z2buf, offs, sN,
                                         stats2, b2g, b2b, Bp, cvb);

    k_ln<<<(NNODE+255)/256, 256, 0, stream>>>(hA, lng, lnb, hLN);
    k_fc1<<<NGR*8, 256, 0, stream>>>(hLN, fw1, partial);
    k_fc2<<<NGR, 128, 0, stream>>>(partial, fb1, fw2, fb2, (float*)d_out);
}

// Round 7
// 468.104 us; speedup vs baseline: 2.6999x; 1.2854x over previous
//
#include <hip/hip_runtime.h>
#include <hip/hip_bf16.h>

#define NNODE 8256
#define NEDGE 132096
#define DD 32
#define HIDN 128
#define NGR 32
#define PERG 258
#define KPG (PERG*DD)      // 8256
#define NSTEP 129          // phase-2 K-steps (128 h-rows + 1 bias row)
#define PADE_MAX 330240    // 8256 * 40 slots (padded CSR capacity)

typedef unsigned short ushortT;
typedef __attribute__((ext_vector_type(8))) short short8v;   // 8 bf16
typedef __attribute__((ext_vector_type(4))) float float4v;   // MFMA 16x16 acc

__device__ __forceinline__ unsigned pk_bf16(float a, float b) {
    unsigned ua = __float_as_uint(a), ub = __float_as_uint(b);
    ua = (ua + 0x7fffu + ((ua >> 16) & 1u)) >> 16;
    ub = (ub + 0x7fffu + ((ub >> 16) & 1u)) >> 16;
    return ua | (ub << 16);
}
__device__ __forceinline__ ushortT bf16s(float a) {
    unsigned ua = __float_as_uint(a);
    return (ushortT)((ua + 0x7fffu + ((ua >> 16) & 1u)) >> 16);
}

// ---------------- node encoders: h[N][32] ----------------
__global__ __launch_bounds__(256) void k_encode(
    const float* __restrict__ pos, const float* __restrict__ vel,
    const float* __restrict__ nw1, const float* __restrict__ nb1,
    const float* __restrict__ nw2, const float* __restrict__ nb2,
    const float* __restrict__ vw1, const float* __restrict__ vb1,
    const float* __restrict__ vw2, const float* __restrict__ vb2,
    float* __restrict__ h)
{
    int i = blockIdx.x * 256 + threadIdx.x;
    if (i >= NNODE) return;
    float p0 = pos[i*3], p1 = pos[i*3+1], p2 = pos[i*3+2];
    float v0 = vel[i*3], v1 = vel[i*3+1], v2 = vel[i*3+2];
    float accP[16], accV[16];
    #pragma unroll
    for (int f = 0; f < 16; f++) { accP[f] = nb2[f]; accV[f] = vb2[f]; }
    for (int j = 0; j < HIDN; j++) {
        float hp = p0*nw1[j] + p1*nw1[128+j] + p2*nw1[256+j] + nb1[j];
        hp = hp >= 0.f ? hp : 0.2f*hp;
        float hv = v0*vw1[j] + v1*vw1[128+j] + v2*vw1[256+j] + vb1[j];
        hv = hv >= 0.f ? hv : 0.2f*hv;
        #pragma unroll
        for (int f = 0; f < 16; f++) {
            accP[f] += hp * nw2[j*16+f];
            accV[f] += hv * vw2[j*16+f];
        }
    }
    #pragma unroll
    for (int f = 0; f < 16; f++) {
        h[(size_t)i*DD + f]      = accP[f];
        h[(size_t)i*DD + 16 + f] = accV[f];
    }
}

// ---------------- per-edge dist, max-dist, degree count ----------------
__global__ __launch_bounds__(256) void k_edge1(
    const float* __restrict__ pos, const int* __restrict__ ei,
    float* __restrict__ dist, unsigned* __restrict__ maxd, int* __restrict__ deg)
{
    int e = blockIdx.x * 256 + threadIdx.x;
    float dd = 0.f;
    if (e < NEDGE) {
        int c = ei[e], n = ei[NEDGE + e];
        float dx = pos[c*3]   - pos[n*3];
        float dy = pos[c*3+1] - pos[n*3+1];
        float dz = pos[c*3+2] - pos[n*3+2];
        dd = sqrtf(dx*dx + dy*dy + dz*dz);
        dist[e] = dd;
        atomicAdd(&deg[c], 1);
    }
    #pragma unroll
    for (int o = 32; o > 0; o >>= 1) dd = fmaxf(dd, __shfl_down(dd, o, 64));
    if ((threadIdx.x & 63) == 0) atomicMax(maxd, __float_as_uint(dd));
}

// ---------------- exclusive scan of PADDED degrees -> padded CSR offsets ----------------
__global__ __launch_bounds__(1024) void k_scan(const int* __restrict__ deg, int* __restrict__ off)
{
    __shared__ int s[1024];
    int t = threadIdx.x;
    int base = t * 9;
    int loc[9]; int sum = 0;
    #pragma unroll
    for (int k = 0; k < 9; k++) {
        int i = base + k;
        int v = (i < NNODE) ? ((deg[i] + 31) & ~31) : 0;   // pad to 32
        loc[k] = sum; sum += v;
    }
    s[t] = sum; __syncthreads();
    for (int o = 1; o < 1024; o <<= 1) {
        int v = (t >= o) ? s[t - o] : 0;
        __syncthreads();
        s[t] += v;
        __syncthreads();
    }
    int pre = (t == 0) ? 0 : s[t-1];
    #pragma unroll
    for (int k = 0; k < 9; k++) {
        int i = base + k;
        if (i < NNODE) off[i] = pre + loc[k];
    }
    if (t == 1023) off[NNODE] = s[1023];
}

// ---------------- scatter edges into padded CSR slots ----------------
__global__ __launch_bounds__(256) void k_scatter(
    const int* __restrict__ ei, const int* __restrict__ off,
    int* __restrict__ cursor, int* __restrict__ sN, int* __restrict__ sE)
{
    int e = blockIdx.x * 256 + threadIdx.x;
    if (e >= NEDGE) return;
    int c = ei[e];
    int p = off[c] + atomicAdd(&cursor[c], 1);
    sN[p] = ei[NEDGE + e];
    sE[p] = e;
}

// ---------------- pack B = [w3 ; b3] into MFMA fragment order (bf16) ----------------
__global__ __launch_bounds__(256) void k_packB(
    const float* __restrict__ w3, const float* __restrict__ b3, ushortT* __restrict__ Bp)
{
    int gid = blockIdx.x*256 + threadIdx.x;
    if (gid >= NSTEP*2*64) return;
    int step = gid >> 7;
    int ntile = (gid >> 6) & 1;
    int lane = gid & 63;
    int col = ntile*16 + (lane & 15);
    int kb = step*32 + 8*(lane >> 4);
    float v[8];
    #pragma unroll
    for (int j = 0; j < 8; j++) {
        int k = kb + j;
        v[j] = (k < 4096) ? w3[(size_t)k*DD + col] : b3[(size_t)(k - 4096)*DD + col];
    }
    uint4 o;
    o.x = pk_bf16(v[0], v[1]);
    o.y = pk_bf16(v[2], v[3]);
    o.z = pk_bf16(v[4], v[5]);
    o.w = pk_bf16(v[6], v[7]);
    *(uint4*)&Bp[(size_t)gid*8] = o;
}

// ---------------- pack W2 into MFMA B-fragment order (bf16) ----------------
// W2p[s2(4)][n(8)][lane][8]: B[k = 32*s2 + 8*(l>>4)+j][col = 16n + (l&15)]
__global__ __launch_bounds__(256) void k_packW2(
    const float* __restrict__ w2, ushortT* __restrict__ W2p)
{
    int gid = blockIdx.x*256 + threadIdx.x;
    if (gid >= 4*8*64) return;
    int s2 = gid >> 9;
    int n  = (gid >> 6) & 7;
    int lane = gid & 63;
    int col = 16*n + (lane & 15);
    int kb = 32*s2 + 8*(lane >> 4);
    float v[8];
    #pragma unroll
    for (int j = 0; j < 8; j++) v[j] = w2[(size_t)(kb + j)*HIDN + col];
    uint4 o;
    o.x = pk_bf16(v[0], v[1]);
    o.y = pk_bf16(v[2], v[3]);
    o.z = pk_bf16(v[4], v[5]);
    o.w = pk_bf16(v[6], v[7]);
    *(uint4*)&W2p[(size_t)gid*8] = o;
}

// ---------------- z2 via MFMA, written TRANSPOSED: z2T[h][padslot] ----------------
// block = 64 slots, wave = 16 slots (one 16x128 C-tile). Row 128 = ones (real) / 0 (pad).
__global__ __launch_bounds__(256, 4) void k_z2(
    const float* __restrict__ dist, const unsigned* __restrict__ maxdb,
    const int* __restrict__ sE, const int* __restrict__ padOff,
    const float* __restrict__ w1, const float* __restrict__ b1,
    const ushortT* __restrict__ W2p, const float* __restrict__ b2,
    ushortT* __restrict__ z2T)
{
    int t = threadIdx.x, wv = t >> 6, ln = t & 63;
    int slotB = blockIdx.x * 64;
    int padE = padOff[NNODE];
    if (slotB >= padE) return;
    int slotW = slotB + wv*16;
    int l16 = ln & 15, lh = ln >> 4;

    // lanes 0..15: w for slot slotW+ln (w = -1 marks pad)
    float wval = -1.f;
    if (ln < 16) {
        int e = sE[slotW + ln];
        if (e >= 0) {
            float inv = 3.14159265358979323846f / __uint_as_float(*maxdb);
            wval = 0.5f * (cosf(dist[e] * inv) + 1.0f);
        }
    }
    float wrow = __shfl(wval, l16, 64);     // w for this lane's A-row (slot)
    bool pad = (wrow < 0.f);

    float4v acc[8];
    #pragma unroll
    for (int n = 0; n < 8; n++) acc[n] = (float4v){0.f,0.f,0.f,0.f};

    #pragma unroll
    for (int s2 = 0; s2 < 4; s2++) {
        int kb = s2*32 + lh*8;
        float4 w1a = *(const float4*)&w1[kb];
        float4 w1b = *(const float4*)&w1[kb+4];
        float4 b1a = *(const float4*)&b1[kb];
        float4 b1b = *(const float4*)&b1[kb+4];
        float z0 = fmaxf(wrow*w1a.x + b1a.x, 0.f);
        float z1 = fmaxf(wrow*w1a.y + b1a.y, 0.f);
        float z2 = fmaxf(wrow*w1a.z + b1a.z, 0.f);
        float z3 = fmaxf(wrow*w1a.w + b1a.w, 0.f);
        float z4 = fmaxf(wrow*w1b.x + b1b.x, 0.f);
        float z5 = fmaxf(wrow*w1b.y + b1b.y, 0.f);
        float z6 = fmaxf(wrow*w1b.z + b1b.z, 0.f);
        float z7 = fmaxf(wrow*w1b.w + b1b.w, 0.f);
        uint4 ua;
        ua.x = pad ? 0u : pk_bf16(z0, z1);
        ua.y = pad ? 0u : pk_bf16(z2, z3);
        ua.z = pad ? 0u : pk_bf16(z4, z5);
        ua.w = pad ? 0u : pk_bf16(z6, z7);
        short8v a = *(short8v*)&ua;
        #pragma unroll
        for (int n = 0; n < 8; n++) {
            short8v b = *(const short8v*)&W2p[(size_t)((s2*8 + n)*64 + ln)*8];
            acc[n] = __builtin_amdgcn_mfma_f32_16x16x32_bf16(a, b, acc[n], 0, 0, 0);
        }
    }

    // store: C row = local slot = 4*lh + r, col = 16n + l16 -> z2T[col][slot]
    float wfl0 = __shfl(wval, 4*lh + 0, 64);
    float wfl1 = __shfl(wval, 4*lh + 1, 64);
    float wfl2 = __shfl(wval, 4*lh + 2, 64);
    float wfl3 = __shfl(wval, 4*lh + 3, 64);
    #pragma unroll
    for (int n = 0; n < 8; n++) {
        int col = 16*n + l16;
        float bb = b2[col];
        float v0 = (wfl0 < 0.f) ? 0.f : fmaxf(acc[n][0] + bb, 0.f);
        float v1 = (wfl1 < 0.f) ? 0.f : fmaxf(acc[n][1] + bb, 0.f);
        float v2 = (wfl2 < 0.f) ? 0.f : fmaxf(acc[n][2] + bb, 0.f);
        float v3 = (wfl3 < 0.f) ? 0.f : fmaxf(acc[n][3] + bb, 0.f);
        uint2 o = make_uint2(pk_bf16(v0, v1), pk_bf16(v2, v3));
        *(uint2*)&z2T[(size_t)col*PADE_MAX + (unsigned)(slotW + 4*lh)] = o;
    }
    // ones-row (h = 128)
    if (wv == 0 && ln < 8) {
        uint4 u;
        ushortT* f = (ushortT*)&u;
        #pragma unroll
        for (int i = 0; i < 8; i++)
            f[i] = (sE[slotB + ln*8 + i] >= 0) ? (ushortT)0x3F80 : (ushortT)0;
        *(uint4*)&z2T[(size_t)128*PADE_MAX + (unsigned)(slotB + ln*8)] = u;
    }
}

// ---------------- BN column stats ----------------
__global__ __launch_bounds__(256) void k_bnstats(const float* __restrict__ h, float* __restrict__ stats)
{
    int t = threadIdx.x;
    float s = 0.f, ss = 0.f;
    for (size_t i = (size_t)blockIdx.x*256 + t; i < (size_t)NNODE*DD; i += (size_t)gridDim.x*256) {
        float v = h[i]; s += v; ss += v*v;
    }
    __shared__ float r0[256], r1[256];
    r0[t] = s; r1[t] = ss;
    __syncthreads();
    if (t < 32) {
        float a = 0.f, b = 0.f;
        for (int k = t; k < 256; k += 32) { a += r0[k]; b += r1[k]; }
        atomicAdd(&stats[t], a);
        atomicAdd(&stats[32 + t], b);
    }
}

// ---------------- gather BN(h) into transposed padded layout: hnT[d][padslot] ----------------
__global__ __launch_bounds__(256) void k_hgather(
    const float* __restrict__ hn, const int* __restrict__ sN, const int* __restrict__ padOff,
    const float* __restrict__ stats,
    const float* __restrict__ bng, const float* __restrict__ bnb,
    ushortT* __restrict__ hnT)
{
    int t = threadIdx.x;
    int slotB = blockIdx.x * 128;
    if (slotB >= padOff[NNODE]) return;
    int d = t >> 3;
    int sb = slotB + (t & 7) * 16;
    float mu  = stats[d] * (1.0f/(float)NNODE);
    float var = stats[DD+d] * (1.0f/(float)NNODE) - mu*mu;
    float sc = rsqrtf(var + 1e-5f) * bng[d];
    float sh = bnb[d] - mu*sc;
    float v[16];
    #pragma unroll
    for (int i = 0; i < 16; i++) {
        int n = sN[sb + i];
        v[i] = (n >= 0) ? (hn[(size_t)n*DD + d]*sc + sh) : 0.f;
    }
    uint4 o0, o1;
    o0.x = pk_bf16(v[0], v[1]);  o0.y = pk_bf16(v[2], v[3]);
    o0.z = pk_bf16(v[4], v[5]);  o0.w = pk_bf16(v[6], v[7]);
    o1.x = pk_bf16(v[8], v[9]);  o1.y = pk_bf16(v[10], v[11]);
    o1.z = pk_bf16(v[12], v[13]);o1.w = pk_bf16(v[14], v[15]);
    *(uint4*)&hnT[(size_t)d*PADE_MAX + sb]     = o0;
    *(uint4*)&hnT[(size_t)d*PADE_MAX + sb + 8] = o1;
}

// ---------------- fused NNConv, both phases MFMA ----------------
// wave w owns center blockIdx.x*4+w.
// Phase 1: G = z2T_frag @ hnT_frag (9 M-tiles x 2 N-tiles), x 1/denom -> sG (bf16, swizzled)
// Phase 2: out = G @ [w3;b3] via Bp (round-5 verified path)
__global__ __launch_bounds__(256, 3) void k_conv(
    const float* __restrict__ hin, float* __restrict__ hout,
    const ushortT* __restrict__ z2T, const ushortT* __restrict__ hnT,
    const int* __restrict__ padOff, const int* __restrict__ deg,
    const ushortT* __restrict__ Bp, const float* __restrict__ convb)
{
    __shared__ ushortT sG[4][4128];      // 33 KB
    __shared__ float sred[4][4][DD];     // 2 KB

    int t = threadIdx.x, wv = t >> 6, ln = t & 63;
    int l16 = ln & 15, lh = ln >> 4;
    int c = blockIdx.x*4 + wv;
    int ks0 = padOff[c], ks1 = padOff[c+1];
    float idc = 1.f / fmaxf((float)deg[c], 1.f);

    float4v acc[9][2];
    #pragma unroll
    for (int m = 0; m < 9; m++) { acc[m][0] = (float4v){0,0,0,0}; acc[m][1] = (float4v){0,0,0,0}; }

    for (int ks = ks0; ks < ks1; ks += 32) {
        size_t kcol = (size_t)(ks + lh*8);
        short8v b0 = *(const short8v*)&hnT[(size_t)l16*PADE_MAX + kcol];
        short8v b1 = *(const short8v*)&hnT[(size_t)(16 + l16)*PADE_MAX + kcol];
        short8v a[9];
        #pragma unroll
        for (int m = 0; m < 9; m++)
            a[m] = *(const short8v*)&z2T[(size_t)(16*m + l16)*PADE_MAX + kcol];
        #pragma unroll
        for (int m = 0; m < 9; m++) {
            acc[m][0] = __builtin_amdgcn_mfma_f32_16x16x32_bf16(a[m], b0, acc[m][0], 0, 0, 0);
            acc[m][1] = __builtin_amdgcn_mfma_f32_16x16x32_bf16(a[m], b1, acc[m][1], 0, 0, 0);
        }
    }

    // write G*idc to swizzled sG: byte = h*64 + ((d*2) ^ (((h>>2)&3)<<4))
    char* sGw = (char*)&sG[wv][0];
    #pragma unroll
    for (int m = 0; m < 9; m++) {
        #pragma unroll
        for (int r = 0; r < 4; r++) {
            int h = 16*m + 4*lh + r;
            bool live = (m < 8) || (lh == 0 && r == 0);   // h<=128
            if (live) {
                unsigned sw = (unsigned)(((h >> 2) & 3) << 4);
                #pragma unroll
                for (int n = 0; n < 2; n++) {
                    int d = 16*n + l16;
                    unsigned byte = (unsigned)(h*64) + (((unsigned)(d*2)) ^ sw);
                    *(ushortT*)(sGw + byte) = bf16s(acc[m][n][r] * idc);
                }
            }
        }
    }
    __syncthreads();

    // phase 2: MFMA over 129 K-steps, strided across waves; A rows = 4 centers
    float4v c0 = (float4v){0,0,0,0}, c1 = (float4v){0,0,0,0};
    for (int s = wv; s < NSTEP; s += 4) {
        short8v a = (short8v){0,0,0,0,0,0,0,0};
        if (l16 < 4) {
            unsigned sw = (unsigned)(((s >> 2) & 3) << 4);
            unsigned byte = (unsigned)(s*64) + (((unsigned)(lh*16)) ^ sw);
            a = *(const short8v*)((const char*)&sG[l16][0] + byte);
        }
        short8v b0 = *(const short8v*)&Bp[((size_t)s*2 + 0)*512 + ln*8];
        short8v b1 = *(const short8v*)&Bp[((size_t)s*2 + 1)*512 + ln*8];
        c0 = __builtin_amdgcn_mfma_f32_16x16x32_bf16(a, b0, c0, 0, 0, 0);
        c1 = __builtin_amdgcn_mfma_f32_16x16x32_bf16(a, b1, c1, 0, 0, 0);
    }
    if (lh == 0) {
        #pragma unroll
        for (int r = 0; r < 4; r++) {
            sred[wv][r][l16]      = c0[r];
            sred[wv][r][16 + l16] = c1[r];
        }
    }
    __syncthreads();

    if (t < 4*DD) {
        int cc = t >> 5, f = t & 31;
        float s = sred[0][cc][f] + sred[1][cc][f] + sred[2][cc][f] + sred[3][cc][f];
        int node = blockIdx.x*4 + cc;
        hout[(size_t)node*DD + f] = s + convb[f] + hin[(size_t)node*DD + f];
    }
}

// ---------------- LayerNorm into hLN ----------------
__global__ __launch_bounds__(256) void k_ln(const float* __restrict__ h,
    const float* __restrict__ lng, const float* __restrict__ lnb, float* __restrict__ hLN)
{
    int i = blockIdx.x * 256 + threadIdx.x;
    if (i >= NNODE) return;
    const float4* hr = (const float4*)(h + (size_t)i*DD);
    float4 v[8];
    float mu = 0.f;
    #pragma unroll
    for (int q = 0; q < 8; q++) { v[q] = hr[q]; mu += v[q].x+v[q].y+v[q].z+v[q].w; }
    mu *= (1.f/32.f);
    float var = 0.f;
    #pragma unroll
    for (int q = 0; q < 8; q++) {
        float d0=v[q].x-mu, d1=v[q].y-mu, d2=v[q].z-mu, d3=v[q].w-mu;
        var += d0*d0 + d1*d1 + d2*d2 + d3*d3;
    }
    var *= (1.f/32.f);
    float rs = rsqrtf(var + 1e-5f);
    float4* o = (float4*)(hLN + (size_t)i*DD);
    #pragma unroll
    for (int q = 0; q < 8; q++) {
        float4 gq = ((const float4*)lng)[q];
        float4 bq = ((const float4*)lnb)[q];
        float4 r;
        r.x = (v[q].x-mu)*rs*gq.x + bq.x;
        r.y = (v[q].y-mu)*rs*gq.y + bq.y;
        r.z = (v[q].z-mu)*rs*gq.z + bq.z;
        r.w = (v[q].w-mu)*rs*gq.w + bq.w;
        o[q] = r;
    }
}

// ---------------- fc1 partial GEMV ----------------
__global__ __launch_bounds__(256) void k_fc1(const float* __restrict__ hLN,
    const float* __restrict__ w1, float* __restrict__ partial)
{
    int g = blockIdx.x >> 3, s = blockIdx.x & 7;
    int j = threadIdx.x & 127, half = threadIdx.x >> 7;
    int k0 = s*1032 + half*4;
    const float* x = hLN + (size_t)g*KPG;
    float a = 0.f;
    #pragma unroll 2
    for (int m = 0; m < 129; m++) {
        int k = k0 + m*8;
        float4 xv = *(const float4*)&x[k];
        const float* wp = w1 + (size_t)k*HIDN + j;
        a += xv.x * wp[0];
        a += xv.y * wp[HIDN];
        a += xv.z * wp[2*HIDN];
        a += xv.w * wp[3*HIDN];
    }
    partial[((size_t)blockIdx.x*2 + half)*HIDN + j] = a;
}

// ---------------- fc2 ----------------
__global__ __launch_bounds__(128) void k_fc2(const float* __restrict__ partial,
    const float* __restrict__ b1, const float* __restrict__ w2,
    const float* __restrict__ b2, float* __restrict__ out)
{
    __shared__ float hid[128];
    int g = blockIdx.x, t = threadIdx.x;
    float a = b1[t];
    #pragma unroll
    for (int p = 0; p < 16; p++) a += partial[(size_t)(g*16 + p)*HIDN + t];
    a = a >= 0.f ? a : 0.2f*a;
    hid[t] = a;
    __syncthreads();
    float o = b2[t];
    #pragma unroll 4
    for (int j = 0; j < 128; j++) o += hid[j]*w2[j*128 + t];
    out[(size_t)g*128 + t] = o;
}

extern "C" void kernel_launch(void* const* d_in, const int* in_sizes, int n_in,
                              void* d_out, int out_size, void* d_ws, size_t ws_size,
                              hipStream_t stream)
{
    const float* pos  = (const float*)d_in[0];
    const float* vel  = (const float*)d_in[1];
    const int*   eidx = (const int*)  d_in[2];
    const float* nw1 = (const float*)d_in[3];  const float* nb1 = (const float*)d_in[4];
    const float* nw2 = (const float*)d_in[5];  const float* nb2 = (const float*)d_in[6];
    const float* vw1 = (const float*)d_in[7];  const float* vb1 = (const float*)d_in[8];
    const float* vw2 = (const float*)d_in[9];  const float* vb2 = (const float*)d_in[10];
    const float* ew1 = (const float*)d_in[11]; const float* eb1 = (const float*)d_in[12];
    const float* ew2 = (const float*)d_in[13]; const float* eb2 = (const float*)d_in[14];
    const float* ew3 = (const float*)d_in[15]; const float* eb3 = (const float*)d_in[16];
    const float* cvb = (const float*)d_in[17];
    const float* b1g = (const float*)d_in[18]; const float* b1b = (const float*)d_in[19];
    const float* b2g = (const float*)d_in[20]; const float* b2b = (const float*)d_in[21];
    const float* lng = (const float*)d_in[22]; const float* lnb = (const float*)d_in[23];
    const float* fw1 = (const float*)d_in[24]; const float* fb1 = (const float*)d_in[25];
    const float* fw2 = (const float*)d_in[26]; const float* fb2 = (const float*)d_in[27];

    char* ws = (char*)d_ws;
    size_t off = 0;
    auto alloc = [&](size_t bytes) -> void* {
        void* p = ws + off;
        off = (off + bytes + 255) & ~(size_t)255;
        return p;
    };
    unsigned* maxd  = (unsigned*)alloc(4);
    float* stats1   = (float*)alloc(64*4);
    float* stats2   = (float*)alloc(64*4);
    int* deg        = (int*)alloc((size_t)NNODE*4);
    int* cursor     = (int*)alloc((size_t)NNODE*4);
    size_t zeroBytes = off;
    int* padOff     = (int*)alloc((size_t)(NNODE+1)*4);
    int* sN         = (int*)alloc((size_t)PADE_MAX*4);
    int* sE         = (int*)alloc((size_t)PADE_MAX*4);
    float* dist     = (float*)alloc((size_t)NEDGE*4);
    float* hA       = (float*)alloc((size_t)NNODE*DD*4);
    float* hB       = (float*)alloc((size_t)NNODE*DD*4);
    float* hLN      = (float*)alloc((size_t)NNODE*DD*4);
    float* partial  = (float*)alloc((size_t)NGR*16*HIDN*4);
    ushortT* Bp     = (ushortT*)alloc((size_t)NSTEP*2*64*8*2);  // 264 KB
    ushortT* W2p    = (ushortT*)alloc((size_t)4*8*64*8*2);      // 32 KB
    ushortT* z2T    = (ushortT*)alloc((size_t)129*PADE_MAX*2);  // 85.2 MB
    ushortT* hnT    = (ushortT*)alloc((size_t)32*PADE_MAX*2);   // 21.1 MB (must follow z2T)

    hipMemsetAsync(d_ws, 0, zeroBytes, stream);
    hipMemsetAsync(sN, 0xFF, (size_t)PADE_MAX*4, stream);
    hipMemsetAsync(sE, 0xFF, (size_t)PADE_MAX*4, stream);

    k_encode<<<(NNODE+255)/256, 256, 0, stream>>>(pos, vel, nw1, nb1, nw2, nb2,
                                                  vw1, vb1, vw2, vb2, hA);
    k_edge1<<<NEDGE/256, 256, 0, stream>>>(pos, eidx, dist, maxd, deg);
    k_scan<<<1, 1024, 0, stream>>>(deg, padOff);
    k_scatter<<<NEDGE/256, 256, 0, stream>>>(eidx, padOff, cursor, sN, sE);
    k_packB<<<(NSTEP*2*64 + 255)/256, 256, 0, stream>>>(ew3, eb3, Bp);
    k_packW2<<<8, 256, 0, stream>>>(ew2, W2p);
    k_z2<<<PADE_MAX/64, 256, 0, stream>>>(dist, maxd, sE, padOff,
                                          ew1, eb1, W2p, eb2, z2T);

    k_bnstats<<<64, 256, 0, stream>>>(hA, stats1);
    k_hgather<<<PADE_MAX/128, 256, 0, stream>>>(hA, sN, padOff, stats1, b1g, b1b, hnT);
    k_conv<<<NNODE/4, 256, 0, stream>>>(hA, hB, z2T, hnT, padOff, deg, Bp, cvb);

    k_bnstats<<<64, 256, 0, stream>>>(hB, stats2);
    k_hgather<<<PADE_MAX/128, 256, 0, stream>>>(hB, sN, padOff, stats2, b2g, b2b, hnT);
    k_conv<<<NNODE/4, 256, 0, stream>>>(hB, hA, z2T, hnT, padOff, deg, Bp, cvb);

    k_ln<<<(NNODE+255)/256, 256, 0, stream>>>(hA, lng, lnb, hLN);
    k_fc1<<<NGR*8, 256, 0, stream>>>(hLN, fw1, partial);
    k_fc2<<<NGR, 128, 0, stream>>>(partial, fb1, fw2, fb2, (float*)d_out);
}

// Round 8
// 416.035 us; speedup vs baseline: 3.0378x; 1.1252x over previous
//
#include <hip/hip_runtime.h>
#include <hip/hip_bf16.h>

#define NNODE 8256
#define NEDGE 132096
#define DD 32
#define HIDN 128
#define NGR 32
#define PERG 258
#define KPG (PERG*DD)      // 8256
#define NSTEP 129          // phase-2 K-steps (128 h-rows + 1 bias row)
#define PADE_MAX 330240    // 8256 * 40 slots (padded CSR capacity)
#define FC1S 43            // fc1 K-slices (43*192 = 8256)

typedef unsigned short ushortT;
typedef __attribute__((ext_vector_type(8))) short short8v;   // 8 bf16
typedef __attribute__((ext_vector_type(4))) float float4v;   // MFMA 16x16 acc

__device__ __forceinline__ unsigned pk_bf16(float a, float b) {
    unsigned ua = __float_as_uint(a), ub = __float_as_uint(b);
    ua = (ua + 0x7fffu + ((ua >> 16) & 1u)) >> 16;
    ub = (ub + 0x7fffu + ((ub >> 16) & 1u)) >> 16;
    return ua | (ub << 16);
}
__device__ __forceinline__ ushortT bf16s(float a) {
    unsigned ua = __float_as_uint(a);
    return (ushortT)((ua + 0x7fffu + ((ua >> 16) & 1u)) >> 16);
}

// ---------------- node encoders: h[N][32], 8-way j-split + LDS weights ----------------
__global__ __launch_bounds__(256) void k_encode(
    const float* __restrict__ pos, const float* __restrict__ vel,
    const float* __restrict__ nw1, const float* __restrict__ nb1,
    const float* __restrict__ nw2, const float* __restrict__ nb2,
    const float* __restrict__ vw1, const float* __restrict__ vb1,
    const float* __restrict__ vw2, const float* __restrict__ vb2,
    float* __restrict__ h)
{
    __shared__ float s_nw1[384], s_nb1[128], s_nw2[2048];
    __shared__ float s_vw1[384], s_vb1[128], s_vw2[2048];
    __shared__ float s_nb2[16], s_vb2[16];
    int t = threadIdx.x;
    for (int i = t; i < 384;  i += 256) { s_nw1[i] = nw1[i]; s_vw1[i] = vw1[i]; }
    for (int i = t; i < 128;  i += 256) { s_nb1[i] = nb1[i]; s_vb1[i] = vb1[i]; }
    for (int i = t; i < 2048; i += 256) { s_nw2[i] = nw2[i]; s_vw2[i] = vw2[i]; }
    if (t < 16) { s_nb2[t] = nb2[t]; s_vb2[t] = vb2[t]; }
    __syncthreads();

    int n = blockIdx.x * 32 + (t >> 3);   // 258 blocks * 32 nodes
    int q = t & 7;                        // j-range [16q, 16q+16)
    float p0 = pos[n*3], p1 = pos[n*3+1], p2 = pos[n*3+2];
    float v0 = vel[n*3], v1 = vel[n*3+1], v2 = vel[n*3+2];
    float accP[16], accV[16];
    #pragma unroll
    for (int f = 0; f < 16; f++) { accP[f] = 0.f; accV[f] = 0.f; }
    int j0 = q * 16;
    #pragma unroll
    for (int jj = 0; jj < 16; jj++) {
        int j = j0 + jj;
        float hp = p0*s_nw1[j] + p1*s_nw1[128+j] + p2*s_nw1[256+j] + s_nb1[j];
        hp = hp >= 0.f ? hp : 0.2f*hp;
        float hv = v0*s_vw1[j] + v1*s_vw1[128+j] + v2*s_vw1[256+j] + s_vb1[j];
        hv = hv >= 0.f ? hv : 0.2f*hv;
        #pragma unroll
        for (int f = 0; f < 16; f++) {
            accP[f] += hp * s_nw2[j*16+f];
            accV[f] += hv * s_vw2[j*16+f];
        }
    }
    // reduce across 8 q-lanes (consecutive lanes in wave)
    #pragma unroll
    for (int o = 1; o < 8; o <<= 1) {
        #pragma unroll
        for (int f = 0; f < 16; f++) {
            accP[f] += __shfl_xor(accP[f], o, 64);
            accV[f] += __shfl_xor(accV[f], o, 64);
        }
    }
    if (q == 0) {
        float4* op = (float4*)(h + (size_t)n*DD);
        #pragma unroll
        for (int m = 0; m < 4; m++)
            op[m] = make_float4(accP[4*m]+s_nb2[4*m], accP[4*m+1]+s_nb2[4*m+1],
                                accP[4*m+2]+s_nb2[4*m+2], accP[4*m+3]+s_nb2[4*m+3]);
        #pragma unroll
        for (int m = 0; m < 4; m++)
            op[4+m] = make_float4(accV[4*m]+s_vb2[4*m], accV[4*m+1]+s_vb2[4*m+1],
                                  accV[4*m+2]+s_vb2[4*m+2], accV[4*m+3]+s_vb2[4*m+3]);
    }
}

// ---------------- per-edge dist, max-dist, degree count ----------------
__global__ __launch_bounds__(256) void k_edge1(
    const float* __restrict__ pos, const int* __restrict__ ei,
    float* __restrict__ dist, unsigned* __restrict__ maxd, int* __restrict__ deg)
{
    int e = blockIdx.x * 256 + threadIdx.x;
    float dd = 0.f;
    if (e < NEDGE) {
        int c = ei[e], n = ei[NEDGE + e];
        float dx = pos[c*3]   - pos[n*3];
        float dy = pos[c*3+1] - pos[n*3+1];
        float dz = pos[c*3+2] - pos[n*3+2];
        dd = sqrtf(dx*dx + dy*dy + dz*dz);
        dist[e] = dd;
        atomicAdd(&deg[c], 1);
    }
    #pragma unroll
    for (int o = 32; o > 0; o >>= 1) dd = fmaxf(dd, __shfl_down(dd, o, 64));
    if ((threadIdx.x & 63) == 0) atomicMax(maxd, __float_as_uint(dd));
}

// ---------------- exclusive scan of PADDED degrees -> padded CSR offsets ----------------
__global__ __launch_bounds__(1024) void k_scan(const int* __restrict__ deg, int* __restrict__ off)
{
    __shared__ int s[1024];
    int t = threadIdx.x;
    int base = t * 9;
    int loc[9]; int sum = 0;
    #pragma unroll
    for (int k = 0; k < 9; k++) {
        int i = base + k;
        int v = (i < NNODE) ? ((deg[i] + 31) & ~31) : 0;   // pad to 32
        loc[k] = sum; sum += v;
    }
    s[t] = sum; __syncthreads();
    for (int o = 1; o < 1024; o <<= 1) {
        int v = (t >= o) ? s[t - o] : 0;
        __syncthreads();
        s[t] += v;
        __syncthreads();
    }
    int pre = (t == 0) ? 0 : s[t-1];
    #pragma unroll
    for (int k = 0; k < 9; k++) {
        int i = base + k;
        if (i < NNODE) off[i] = pre + loc[k];
    }
    if (t == 1023) off[NNODE] = s[1023];
}

// ---------------- scatter edges into padded CSR slots ----------------
__global__ __launch_bounds__(256) void k_scatter(
    const int* __restrict__ ei, const int* __restrict__ off,
    int* __restrict__ cursor, int* __restrict__ sN, int* __restrict__ sE)
{
    int e = blockIdx.x * 256 + threadIdx.x;
    if (e >= NEDGE) return;
    int c = ei[e];
    int p = off[c] + atomicAdd(&cursor[c], 1);
    sN[p] = ei[NEDGE + e];
    sE[p] = e;
}

// ---------------- pack B = [w3 ; b3] into MFMA fragment order (bf16) ----------------
__global__ __launch_bounds__(256) void k_packB(
    const float* __restrict__ w3, const float* __restrict__ b3, ushortT* __restrict__ Bp)
{
    int gid = blockIdx.x*256 + threadIdx.x;
    if (gid >= NSTEP*2*64) return;
    int step = gid >> 7;
    int ntile = (gid >> 6) & 1;
    int lane = gid & 63;
    int col = ntile*16 + (lane & 15);
    int kb = step*32 + 8*(lane >> 4);
    float v[8];
    #pragma unroll
    for (int j = 0; j < 8; j++) {
        int k = kb + j;
        v[j] = (k < 4096) ? w3[(size_t)k*DD + col] : b3[(size_t)(k - 4096)*DD + col];
    }
    uint4 o;
    o.x = pk_bf16(v[0], v[1]);
    o.y = pk_bf16(v[2], v[3]);
    o.z = pk_bf16(v[4], v[5]);
    o.w = pk_bf16(v[6], v[7]);
    *(uint4*)&Bp[(size_t)gid*8] = o;
}

// ---------------- pack W2 into MFMA B-fragment order (bf16) ----------------
__global__ __launch_bounds__(256) void k_packW2(
    const float* __restrict__ w2, ushortT* __restrict__ W2p)
{
    int gid = blockIdx.x*256 + threadIdx.x;
    if (gid >= 4*8*64) return;
    int s2 = gid >> 9;
    int n  = (gid >> 6) & 7;
    int lane = gid & 63;
    int col = 16*n + (lane & 15);
    int kb = 32*s2 + 8*(lane >> 4);
    float v[8];
    #pragma unroll
    for (int j = 0; j < 8; j++) v[j] = w2[(size_t)(kb + j)*HIDN + col];
    uint4 o;
    o.x = pk_bf16(v[0], v[1]);
    o.y = pk_bf16(v[2], v[3]);
    o.z = pk_bf16(v[4], v[5]);
    o.w = pk_bf16(v[6], v[7]);
    *(uint4*)&W2p[(size_t)gid*8] = o;
}

// ---------------- z2 via MFMA, written TRANSPOSED: z2T[h][padslot] ----------------
__global__ __launch_bounds__(256, 4) void k_z2(
    const float* __restrict__ dist, const unsigned* __restrict__ maxdb,
    const int* __restrict__ sE, const int* __restrict__ padOff,
    const float* __restrict__ w1, const float* __restrict__ b1,
    const ushortT* __restrict__ W2p, const float* __restrict__ b2,
    ushortT* __restrict__ z2T)
{
    int t = threadIdx.x, wv = t >> 6, ln = t & 63;
    int slotB = blockIdx.x * 64;
    int padE = padOff[NNODE];
    if (slotB >= padE) return;
    int slotW = slotB + wv*16;
    int l16 = ln & 15, lh = ln >> 4;

    float wval = -1.f;
    if (ln < 16) {
        int e = sE[slotW + ln];
        if (e >= 0) {
            float inv = 3.14159265358979323846f / __uint_as_float(*maxdb);
            wval = 0.5f * (cosf(dist[e] * inv) + 1.0f);
        }
    }
    float wrow = __shfl(wval, l16, 64);
    bool pad = (wrow < 0.f);

    float4v acc[8];
    #pragma unroll
    for (int n = 0; n < 8; n++) acc[n] = (float4v){0.f,0.f,0.f,0.f};

    #pragma unroll
    for (int s2 = 0; s2 < 4; s2++) {
        int kb = s2*32 + lh*8;
        float4 w1a = *(const float4*)&w1[kb];
        float4 w1b = *(const float4*)&w1[kb+4];
        float4 b1a = *(const float4*)&b1[kb];
        float4 b1b = *(const float4*)&b1[kb+4];
        float z0 = fmaxf(wrow*w1a.x + b1a.x, 0.f);
        float z1 = fmaxf(wrow*w1a.y + b1a.y, 0.f);
        float z2 = fmaxf(wrow*w1a.z + b1a.z, 0.f);
        float z3 = fmaxf(wrow*w1a.w + b1a.w, 0.f);
        float z4 = fmaxf(wrow*w1b.x + b1b.x, 0.f);
        float z5 = fmaxf(wrow*w1b.y + b1b.y, 0.f);
        float z6 = fmaxf(wrow*w1b.z + b1b.z, 0.f);
        float z7 = fmaxf(wrow*w1b.w + b1b.w, 0.f);
        uint4 ua;
        ua.x = pad ? 0u : pk_bf16(z0, z1);
        ua.y = pad ? 0u : pk_bf16(z2, z3);
        ua.z = pad ? 0u : pk_bf16(z4, z5);
        ua.w = pad ? 0u : pk_bf16(z6, z7);
        short8v a = *(short8v*)&ua;
        #pragma unroll
        for (int n = 0; n < 8; n++) {
            short8v b = *(const short8v*)&W2p[(size_t)((s2*8 + n)*64 + ln)*8];
            acc[n] = __builtin_amdgcn_mfma_f32_16x16x32_bf16(a, b, acc[n], 0, 0, 0);
        }
    }

    float wfl0 = __shfl(wval, 4*lh + 0, 64);
    float wfl1 = __shfl(wval, 4*lh + 1, 64);
    float wfl2 = __shfl(wval, 4*lh + 2, 64);
    float wfl3 = __shfl(wval, 4*lh + 3, 64);
    #pragma unroll
    for (int n = 0; n < 8; n++) {
        int col = 16*n + l16;
        float bb = b2[col];
        float v0 = (wfl0 < 0.f) ? 0.f : fmaxf(acc[n][0] + bb, 0.f);
        float v1 = (wfl1 < 0.f) ? 0.f : fmaxf(acc[n][1] + bb, 0.f);
        float v2 = (wfl2 < 0.f) ? 0.f : fmaxf(acc[n][2] + bb, 0.f);
        float v3 = (wfl3 < 0.f) ? 0.f : fmaxf(acc[n][3] + bb, 0.f);
        uint2 o = make_uint2(pk_bf16(v0, v1), pk_bf16(v2, v3));
        *(uint2*)&z2T[(size_t)col*PADE_MAX + (unsigned)(slotW + 4*lh)] = o;
    }
    if (wv == 0 && ln < 8) {
        uint4 u;
        ushortT* f = (ushortT*)&u;
        #pragma unroll
        for (int i = 0; i < 8; i++)
            f[i] = (sE[slotB + ln*8 + i] >= 0) ? (ushortT)0x3F80 : (ushortT)0;
        *(uint4*)&z2T[(size_t)128*PADE_MAX + (unsigned)(slotB + ln*8)] = u;
    }
}

// ---------------- BN column stats ----------------
__global__ __launch_bounds__(256) void k_bnstats(const float* __restrict__ h, float* __restrict__ stats)
{
    int t = threadIdx.x;
    float s = 0.f, ss = 0.f;
    for (size_t i = (size_t)blockIdx.x*256 + t; i < (size_t)NNODE*DD; i += (size_t)gridDim.x*256) {
        float v = h[i]; s += v; ss += v*v;
    }
    __shared__ float r0[256], r1[256];
    r0[t] = s; r1[t] = ss;
    __syncthreads();
    if (t < 32) {
        float a = 0.f, b = 0.f;
        for (int k = t; k < 256; k += 32) { a += r0[k]; b += r1[k]; }
        atomicAdd(&stats[t], a);
        atomicAdd(&stats[32 + t], b);
    }
}

// ---------------- gather BN(h) into transposed padded layout: hnT[d][padslot] ----------------
__global__ __launch_bounds__(256) void k_hgather(
    const float* __restrict__ hn, const int* __restrict__ sN, const int* __restrict__ padOff,
    const float* __restrict__ stats,
    const float* __restrict__ bng, const float* __restrict__ bnb,
    ushortT* __restrict__ hnT)
{
    int t = threadIdx.x;
    int slotB = blockIdx.x * 128;
    if (slotB >= padOff[NNODE]) return;
    int d = t >> 3;
    int sb = slotB + (t & 7) * 16;
    float mu  = stats[d] * (1.0f/(float)NNODE);
    float var = stats[DD+d] * (1.0f/(float)NNODE) - mu*mu;
    float sc = rsqrtf(var + 1e-5f) * bng[d];
    float sh = bnb[d] - mu*sc;
    float v[16];
    #pragma unroll
    for (int i = 0; i < 16; i++) {
        int n = sN[sb + i];
        v[i] = (n >= 0) ? (hn[(size_t)n*DD + d]*sc + sh) : 0.f;
    }
    uint4 o0, o1;
    o0.x = pk_bf16(v[0], v[1]);  o0.y = pk_bf16(v[2], v[3]);
    o0.z = pk_bf16(v[4], v[5]);  o0.w = pk_bf16(v[6], v[7]);
    o1.x = pk_bf16(v[8], v[9]);  o1.y = pk_bf16(v[10], v[11]);
    o1.z = pk_bf16(v[12], v[13]);o1.w = pk_bf16(v[14], v[15]);
    *(uint4*)&hnT[(size_t)d*PADE_MAX + sb]     = o0;
    *(uint4*)&hnT[(size_t)d*PADE_MAX + sb + 8] = o1;
}

// ---------------- fused NNConv, both phases MFMA ----------------
__global__ __launch_bounds__(256, 3) void k_conv(
    const float* __restrict__ hin, float* __restrict__ hout,
    const ushortT* __restrict__ z2T, const ushortT* __restrict__ hnT,
    const int* __restrict__ padOff, const int* __restrict__ deg,
    const ushortT* __restrict__ Bp, const float* __restrict__ convb)
{
    __shared__ ushortT sG[4][4128];      // 33 KB
    __shared__ float sred[4][4][DD];     // 2 KB

    int t = threadIdx.x, wv = t >> 6, ln = t & 63;
    int l16 = ln & 15, lh = ln >> 4;
    int c = blockIdx.x*4 + wv;
    int ks0 = padOff[c], ks1 = padOff[c+1];
    float idc = 1.f / fmaxf((float)deg[c], 1.f);

    float4v acc[9][2];
    #pragma unroll
    for (int m = 0; m < 9; m++) { acc[m][0] = (float4v){0,0,0,0}; acc[m][1] = (float4v){0,0,0,0}; }

    for (int ks = ks0; ks < ks1; ks += 32) {
        size_t kcol = (size_t)(ks + lh*8);
        short8v b0 = *(const short8v*)&hnT[(size_t)l16*PADE_MAX + kcol];
        short8v b1 = *(const short8v*)&hnT[(size_t)(16 + l16)*PADE_MAX + kcol];
        short8v a[9];
        #pragma unroll
        for (int m = 0; m < 9; m++)
            a[m] = *(const short8v*)&z2T[(size_t)(16*m + l16)*PADE_MAX + kcol];
        #pragma unroll
        for (int m = 0; m < 9; m++) {
            acc[m][0] = __builtin_amdgcn_mfma_f32_16x16x32_bf16(a[m], b0, acc[m][0], 0, 0, 0);
            acc[m][1] = __builtin_amdgcn_mfma_f32_16x16x32_bf16(a[m], b1, acc[m][1], 0, 0, 0);
        }
    }

    char* sGw = (char*)&sG[wv][0];
    #pragma unroll
    for (int m = 0; m < 9; m++) {
        #pragma unroll
        for (int r = 0; r < 4; r++) {
            int h = 16*m + 4*lh + r;
            bool live = (m < 8) || (lh == 0 && r == 0);   // h<=128
            if (live) {
                unsigned sw = (unsigned)(((h >> 2) & 3) << 4);
                #pragma unroll
                for (int n = 0; n < 2; n++) {
                    int d = 16*n + l16;
                    unsigned byte = (unsigned)(h*64) + (((unsigned)(d*2)) ^ sw);
                    *(ushortT*)(sGw + byte) = bf16s(acc[m][n][r] * idc);
                }
            }
        }
    }
    __syncthreads();

    float4v c0 = (float4v){0,0,0,0}, c1 = (float4v){0,0,0,0};
    for (int s = wv; s < NSTEP; s += 4) {
        short8v a = (short8v){0,0,0,0,0,0,0,0};
        if (l16 < 4) {
            unsigned sw = (unsigned)(((s >> 2) & 3) << 4);
            unsigned byte = (unsigned)(s*64) + (((unsigned)(lh*16)) ^ sw);
            a = *(const short8v*)((const char*)&sG[l16][0] + byte);
        }
        short8v b0 = *(const short8v*)&Bp[((size_t)s*2 + 0)*512 + ln*8];
        short8v b1 = *(const short8v*)&Bp[((size_t)s*2 + 1)*512 + ln*8];
        c0 = __builtin_amdgcn_mfma_f32_16x16x32_bf16(a, b0, c0, 0, 0, 0);
        c1 = __builtin_amdgcn_mfma_f32_16x16x32_bf16(a, b1, c1, 0, 0, 0);
    }
    if (lh == 0) {
        #pragma unroll
        for (int r = 0; r < 4; r++) {
            sred[wv][r][l16]      = c0[r];
            sred[wv][r][16 + l16] = c1[r];
        }
    }
    __syncthreads();

    if (t < 4*DD) {
        int cc = t >> 5, f = t & 31;
        float s = sred[0][cc][f] + sred[1][cc][f] + sred[2][cc][f] + sred[3][cc][f];
        int node = blockIdx.x*4 + cc;
        hout[(size_t)node*DD + f] = s + convb[f] + hin[(size_t)node*DD + f];
    }
}

// ---------------- LayerNorm into hLN ----------------
__global__ __launch_bounds__(256) void k_ln(const float* __restrict__ h,
    const float* __restrict__ lng, const float* __restrict__ lnb, float* __restrict__ hLN)
{
    int i = blockIdx.x * 256 + threadIdx.x;
    if (i >= NNODE) return;
    const float4* hr = (const float4*)(h + (size_t)i*DD);
    float4 v[8];
    float mu = 0.f;
    #pragma unroll
    for (int q = 0; q < 8; q++) { v[q] = hr[q]; mu += v[q].x+v[q].y+v[q].z+v[q].w; }
    mu *= (1.f/32.f);
    float var = 0.f;
    #pragma unroll
    for (int q = 0; q < 8; q++) {
        float d0=v[q].x-mu, d1=v[q].y-mu, d2=v[q].z-mu, d3=v[q].w-mu;
        var += d0*d0 + d1*d1 + d2*d2 + d3*d3;
    }
    var *= (1.f/32.f);
    float rs = rsqrtf(var + 1e-5f);
    float4* o = (float4*)(hLN + (size_t)i*DD);
    #pragma unroll
    for (int q = 0; q < 8; q++) {
        float4 gq = ((const float4*)lng)[q];
        float4 bq = ((const float4*)lnb)[q];
        float4 r;
        r.x = (v[q].x-mu)*rs*gq.x + bq.x;
        r.y = (v[q].y-mu)*rs*gq.y + bq.y;
        r.z = (v[q].z-mu)*rs*gq.z + bq.z;
        r.w = (v[q].w-mu)*rs*gq.w + bq.w;
        o[q] = r;
    }
}

// ---------------- fc1 partial GEMV: 43 K-slices x 32 graphs ----------------
__global__ __launch_bounds__(256) void k_fc1(const float* __restrict__ hLN,
    const float* __restrict__ w1, float* __restrict__ partial)
{
    int g = blockIdx.x / FC1S, s = blockIdx.x % FC1S;
    int j = threadIdx.x & 127, half = threadIdx.x >> 7;
    int k0 = s*192 + half*4;
    const float* x = hLN + (size_t)g*KPG;
    float a = 0.f;
    #pragma unroll
    for (int m = 0; m < 24; m++) {
        int k = k0 + m*8;
        float4 xv = *(const float4*)&x[k];
        const float* wp = w1 + (size_t)k*HIDN + j;
        a += xv.x * wp[0];
        a += xv.y * wp[HIDN];
        a += xv.z * wp[2*HIDN];
        a += xv.w * wp[3*HIDN];
    }
    partial[((size_t)blockIdx.x*2 + half)*HIDN + j] = a;
}

// ---------------- fc2: reduce 86 partials, lrelu, final GEMV ----------------
__global__ __launch_bounds__(128) void k_fc2(const float* __restrict__ partial,
    const float* __restrict__ b1, const float* __restrict__ w2,
    const float* __restrict__ b2, float* __restrict__ out)
{
    __shared__ float hid[128];
    int g = blockIdx.x, t = threadIdx.x;
    float a = b1[t];
    #pragma unroll 2
    for (int p = 0; p < 2*FC1S; p++) a += partial[(size_t)(g*2*FC1S + p)*HIDN + t];
    a = a >= 0.f ? a : 0.2f*a;
    hid[t] = a;
    __syncthreads();
    float o = b2[t];
    #pragma unroll 4
    for (int j = 0; j < 128; j++) o += hid[j]*w2[j*128 + t];
    out[(size_t)g*128 + t] = o;
}

extern "C" void kernel_launch(void* const* d_in, const int* in_sizes, int n_in,
                              void* d_out, int out_size, void* d_ws, size_t ws_size,
                              hipStream_t stream)
{
    const float* pos  = (const float*)d_in[0];
    const float* vel  = (const float*)d_in[1];
    const int*   eidx = (const int*)  d_in[2];
    const float* nw1 = (const float*)d_in[3];  const float* nb1 = (const float*)d_in[4];
    const float* nw2 = (const float*)d_in[5];  const float* nb2 = (const float*)d_in[6];
    const float* vw1 = (const float*)d_in[7];  const float* vb1 = (const float*)d_in[8];
    const float* vw2 = (const float*)d_in[9];  const float* vb2 = (const float*)d_in[10];
    const float* ew1 = (const float*)d_in[11]; const float* eb1 = (const float*)d_in[12];
    const float* ew2 = (const float*)d_in[13]; const float* eb2 = (const float*)d_in[14];
    const float* ew3 = (const float*)d_in[15]; const float* eb3 = (const float*)d_in[16];
    const float* cvb = (const float*)d_in[17];
    const float* b1g = (const float*)d_in[18]; const float* b1b = (const float*)d_in[19];
    const float* b2g = (const float*)d_in[20]; const float* b2b = (const float*)d_in[21];
    const float* lng = (const float*)d_in[22]; const float* lnb = (const float*)d_in[23];
    const float* fw1 = (const float*)d_in[24]; const float* fb1 = (const float*)d_in[25];
    const float* fw2 = (const float*)d_in[26]; const float* fb2 = (const float*)d_in[27];

    char* ws = (char*)d_ws;
    size_t off = 0;
    auto alloc = [&](size_t bytes) -> void* {
        void* p = ws + off;
        off = (off + bytes + 255) & ~(size_t)255;
        return p;
    };
    unsigned* maxd  = (unsigned*)alloc(4);
    float* stats1   = (float*)alloc(64*4);
    float* stats2   = (float*)alloc(64*4);
    int* deg        = (int*)alloc((size_t)NNODE*4);
    int* cursor     = (int*)alloc((size_t)NNODE*4);
    size_t zeroBytes = off;
    int* padOff     = (int*)alloc((size_t)(NNODE+1)*4);
    int* sN         = (int*)alloc((size_t)PADE_MAX*4);
    int* sE         = (int*)alloc((size_t)PADE_MAX*4);
    float* dist     = (float*)alloc((size_t)NEDGE*4);
    float* hA       = (float*)alloc((size_t)NNODE*DD*4);
    float* hB       = (float*)alloc((size_t)NNODE*DD*4);
    float* hLN      = (float*)alloc((size_t)NNODE*DD*4);
    float* partial  = (float*)alloc((size_t)NGR*2*FC1S*HIDN*4);
    ushortT* Bp     = (ushortT*)alloc((size_t)NSTEP*2*64*8*2);  // 264 KB
    ushortT* W2p    = (ushortT*)alloc((size_t)4*8*64*8*2);      // 32 KB
    ushortT* z2T    = (ushortT*)alloc((size_t)129*PADE_MAX*2);  // 85.2 MB
    ushortT* hnT    = (ushortT*)alloc((size_t)32*PADE_MAX*2);   // 21.1 MB

    hipMemsetAsync(d_ws, 0, zeroBytes, stream);
    hipMemsetAsync(sN, 0xFF, (size_t)PADE_MAX*4, stream);
    hipMemsetAsync(sE, 0xFF, (size_t)PADE_MAX*4, stream);

    k_encode<<<NNODE/32, 256, 0, stream>>>(pos, vel, nw1, nb1, nw2, nb2,
                                           vw1, vb1, vw2, vb2, hA);
    k_edge1<<<NEDGE/256, 256, 0, stream>>>(pos, eidx, dist, maxd, deg);
    k_scan<<<1, 1024, 0, stream>>>(deg, padOff);
    k_scatter<<<NEDGE/256, 256, 0, stream>>>(eidx, padOff, cursor, sN, sE);
    k_packB<<<(NSTEP*2*64 + 255)/256, 256, 0, stream>>>(ew3, eb3, Bp);
    k_packW2<<<8, 256, 0, stream>>>(ew2, W2p);
    k_z2<<<PADE_MAX/64, 256, 0, stream>>>(dist, maxd, sE, padOff,
                                          ew1, eb1, W2p, eb2, z2T);

    k_bnstats<<<64, 256, 0, stream>>>(hA, stats1);
    k_hgather<<<PADE_MAX/128, 256, 0, stream>>>(hA, sN, padOff, stats1, b1g, b1b, hnT);
    k_conv<<<NNODE/4, 256, 0, stream>>>(hA, hB, z2T, hnT, padOff, deg, Bp, cvb);

    k_bnstats<<<64, 256, 0, stream>>>(hB, stats2);
    k_hgather<<<PADE_MAX/128, 256, 0, stream>>>(hB, sN, padOff, stats2, b2g, b2b, hnT);
    k_conv<<<NNODE/4, 256, 0, stream>>>(hB, hA, z2T, hnT, padOff, deg, Bp, cvb);

    k_ln<<<(NNODE+255)/256, 256, 0, stream>>>(hA, lng, lnb, hLN);
    k_fc1<<<NGR*FC1S, 256, 0, stream>>>(hLN, fw1, partial);
    k_fc2<<<NGR, 128, 0, stream>>>(partial, fb1, fw2, fb2, (float*)d_out);
}

// Round 9
// 408.859 us; speedup vs baseline: 3.0911x; 1.0176x over previous
//
#include <hip/hip_runtime.h>
#include <hip/hip_bf16.h>

#define NNODE 8256
#define NEDGE 132096
#define DD 32
#define HIDN 128
#define NGR 32
#define PERG 258
#define KPG (PERG*DD)      // 8256
#define NSTEP 129          // phase-2 K-steps (128 h-rows + 1 bias row)
#define PADE_MAX 330240    // 8256 * 40 slots (padded CSR capacity)
#define FC1S 86            // fc1 K-slices (86*96 = 8256)

typedef unsigned short ushortT;
typedef __attribute__((ext_vector_type(8))) short short8v;   // 8 bf16
typedef __attribute__((ext_vector_type(4))) float float4v;   // MFMA 16x16 acc

__device__ __forceinline__ unsigned pk_bf16(float a, float b) {
    unsigned ua = __float_as_uint(a), ub = __float_as_uint(b);
    ua = (ua + 0x7fffu + ((ua >> 16) & 1u)) >> 16;
    ub = (ub + 0x7fffu + ((ub >> 16) & 1u)) >> 16;
    return ua | (ub << 16);
}
__device__ __forceinline__ ushortT bf16s(float a) {
    unsigned ua = __float_as_uint(a);
    return (ushortT)((ua + 0x7fffu + ((ua >> 16) & 1u)) >> 16);
}

// ---------------- node encoders: h[N][32], 8-way j-split + LDS weights ----------------
__global__ __launch_bounds__(256) void k_encode(
    const float* __restrict__ pos, const float* __restrict__ vel,
    const float* __restrict__ nw1, const float* __restrict__ nb1,
    const float* __restrict__ nw2, const float* __restrict__ nb2,
    const float* __restrict__ vw1, const float* __restrict__ vb1,
    const float* __restrict__ vw2, const float* __restrict__ vb2,
    float* __restrict__ h)
{
    __shared__ float s_nw1[384], s_nb1[128], s_nw2[2048];
    __shared__ float s_vw1[384], s_vb1[128], s_vw2[2048];
    __shared__ float s_nb2[16], s_vb2[16];
    int t = threadIdx.x;
    for (int i = t; i < 384;  i += 256) { s_nw1[i] = nw1[i]; s_vw1[i] = vw1[i]; }
    for (int i = t; i < 128;  i += 256) { s_nb1[i] = nb1[i]; s_vb1[i] = vb1[i]; }
    for (int i = t; i < 2048; i += 256) { s_nw2[i] = nw2[i]; s_vw2[i] = vw2[i]; }
    if (t < 16) { s_nb2[t] = nb2[t]; s_vb2[t] = vb2[t]; }
    __syncthreads();

    int n = blockIdx.x * 32 + (t >> 3);
    int q = t & 7;
    float p0 = pos[n*3], p1 = pos[n*3+1], p2 = pos[n*3+2];
    float v0 = vel[n*3], v1 = vel[n*3+1], v2 = vel[n*3+2];
    float accP[16], accV[16];
    #pragma unroll
    for (int f = 0; f < 16; f++) { accP[f] = 0.f; accV[f] = 0.f; }
    int j0 = q * 16;
    #pragma unroll
    for (int jj = 0; jj < 16; jj++) {
        int j = j0 + jj;
        float hp = p0*s_nw1[j] + p1*s_nw1[128+j] + p2*s_nw1[256+j] + s_nb1[j];
        hp = hp >= 0.f ? hp : 0.2f*hp;
        float hv = v0*s_vw1[j] + v1*s_vw1[128+j] + v2*s_vw1[256+j] + s_vb1[j];
        hv = hv >= 0.f ? hv : 0.2f*hv;
        #pragma unroll
        for (int f = 0; f < 16; f++) {
            accP[f] += hp * s_nw2[j*16+f];
            accV[f] += hv * s_vw2[j*16+f];
        }
    }
    #pragma unroll
    for (int o = 1; o < 8; o <<= 1) {
        #pragma unroll
        for (int f = 0; f < 16; f++) {
            accP[f] += __shfl_xor(accP[f], o, 64);
            accV[f] += __shfl_xor(accV[f], o, 64);
        }
    }
    if (q == 0) {
        float4* op = (float4*)(h + (size_t)n*DD);
        #pragma unroll
        for (int m = 0; m < 4; m++)
            op[m] = make_float4(accP[4*m]+s_nb2[4*m], accP[4*m+1]+s_nb2[4*m+1],
                                accP[4*m+2]+s_nb2[4*m+2], accP[4*m+3]+s_nb2[4*m+3]);
        #pragma unroll
        for (int m = 0; m < 4; m++)
            op[4+m] = make_float4(accV[4*m]+s_vb2[4*m], accV[4*m+1]+s_vb2[4*m+1],
                                  accV[4*m+2]+s_vb2[4*m+2], accV[4*m+3]+s_vb2[4*m+3]);
    }
}

// ---------------- per-edge dist, max-dist, degree count ----------------
__global__ __launch_bounds__(256) void k_edge1(
    const float* __restrict__ pos, const int* __restrict__ ei,
    float* __restrict__ dist, unsigned* __restrict__ maxd, int* __restrict__ deg)
{
    int e = blockIdx.x * 256 + threadIdx.x;
    float dd = 0.f;
    if (e < NEDGE) {
        int c = ei[e], n = ei[NEDGE + e];
        float dx = pos[c*3]   - pos[n*3];
        float dy = pos[c*3+1] - pos[n*3+1];
        float dz = pos[c*3+2] - pos[n*3+2];
        dd = sqrtf(dx*dx + dy*dy + dz*dz);
        dist[e] = dd;
        atomicAdd(&deg[c], 1);
    }
    #pragma unroll
    for (int o = 32; o > 0; o >>= 1) dd = fmaxf(dd, __shfl_down(dd, o, 64));
    if ((threadIdx.x & 63) == 0) atomicMax(maxd, __float_as_uint(dd));
}

// ---------------- exclusive scan of PADDED degrees -> padded CSR offsets ----------------
__global__ __launch_bounds__(1024) void k_scan(const int* __restrict__ deg, int* __restrict__ off)
{
    __shared__ int s[1024];
    int t = threadIdx.x;
    int base = t * 9;
    int loc[9]; int sum = 0;
    #pragma unroll
    for (int k = 0; k < 9; k++) {
        int i = base + k;
        int v = (i < NNODE) ? ((deg[i] + 31) & ~31) : 0;   // pad to 32
        loc[k] = sum; sum += v;
    }
    s[t] = sum; __syncthreads();
    for (int o = 1; o < 1024; o <<= 1) {
        int v = (t >= o) ? s[t - o] : 0;
        __syncthreads();
        s[t] += v;
        __syncthreads();
    }
    int pre = (t == 0) ? 0 : s[t-1];
    #pragma unroll
    for (int k = 0; k < 9; k++) {
        int i = base + k;
        if (i < NNODE) off[i] = pre + loc[k];
    }
    if (t == 1023) off[NNODE] = s[1023];
}

// ---------------- scatter edges into padded CSR slots ----------------
__global__ __launch_bounds__(256) void k_scatter(
    const int* __restrict__ ei, const int* __restrict__ off,
    int* __restrict__ cursor, int* __restrict__ sN, int* __restrict__ sE)
{
    int e = blockIdx.x * 256 + threadIdx.x;
    if (e >= NEDGE) return;
    int c = ei[e];
    int p = off[c] + atomicAdd(&cursor[c], 1);
    sN[p] = ei[NEDGE + e];
    sE[p] = e;
}

// ---------------- pack B = [w3 ; b3] into MFMA fragment order (bf16) ----------------
__global__ __launch_bounds__(256) void k_packB(
    const float* __restrict__ w3, const float* __restrict__ b3, ushortT* __restrict__ Bp)
{
    int gid = blockIdx.x*256 + threadIdx.x;
    if (gid >= NSTEP*2*64) return;
    int step = gid >> 7;
    int ntile = (gid >> 6) & 1;
    int lane = gid & 63;
    int col = ntile*16 + (lane & 15);
    int kb = step*32 + 8*(lane >> 4);
    float v[8];
    #pragma unroll
    for (int j = 0; j < 8; j++) {
        int k = kb + j;
        v[j] = (k < 4096) ? w3[(size_t)k*DD + col] : b3[(size_t)(k - 4096)*DD + col];
    }
    uint4 o;
    o.x = pk_bf16(v[0], v[1]);
    o.y = pk_bf16(v[2], v[3]);
    o.z = pk_bf16(v[4], v[5]);
    o.w = pk_bf16(v[6], v[7]);
    *(uint4*)&Bp[(size_t)gid*8] = o;
}

// ---------------- pack W2 into MFMA B-fragment order (bf16) ----------------
__global__ __launch_bounds__(256) void k_packW2(
    const float* __restrict__ w2, ushortT* __restrict__ W2p)
{
    int gid = blockIdx.x*256 + threadIdx.x;
    if (gid >= 4*8*64) return;
    int s2 = gid >> 9;
    int n  = (gid >> 6) & 7;
    int lane = gid & 63;
    int col = 16*n + (lane & 15);
    int kb = 32*s2 + 8*(lane >> 4);
    float v[8];
    #pragma unroll
    for (int j = 0; j < 8; j++) v[j] = w2[(size_t)(kb + j)*HIDN + col];
    uint4 o;
    o.x = pk_bf16(v[0], v[1]);
    o.y = pk_bf16(v[2], v[3]);
    o.z = pk_bf16(v[4], v[5]);
    o.w = pk_bf16(v[6], v[7]);
    *(uint4*)&W2p[(size_t)gid*8] = o;
}

// ---------------- z2 via MFMA, transposed z2T[h][padslot]; pad-skip ----------------
// Pad slots keep garbage in z2T (hnT is 0 there -> contributes exact 0 in conv).
__global__ __launch_bounds__(256, 4) void k_z2(
    const float* __restrict__ dist, const unsigned* __restrict__ maxdb,
    const int* __restrict__ sE, const int* __restrict__ padOff,
    const float* __restrict__ w1, const float* __restrict__ b1,
    const ushortT* __restrict__ W2p, const float* __restrict__ b2,
    ushortT* __restrict__ z2T)
{
    int t = threadIdx.x, wv = t >> 6, ln = t & 63;
    int slotB = blockIdx.x * 64;
    int padE = padOff[NNODE];
    if (slotB >= padE) return;
    int slotW = slotB + wv*16;
    int l16 = ln & 15, lh = ln >> 4;

    float wval = -1.f;
    if (ln < 16) {
        int e = sE[slotW + ln];
        if (e >= 0) {
            float inv = 3.14159265358979323846f / __uint_as_float(*maxdb);
            wval = 0.5f * (cosf(dist[e] * inv) + 1.0f);
        }
    }

    // ones-row (h=128): unconditional 1.0 (pads harmless: hnT=0 there)
    if (wv == 0 && ln < 8) {
        uint4 u = make_uint4(0x3F803F80u, 0x3F803F80u, 0x3F803F80u, 0x3F803F80u);
        *(uint4*)&z2T[(size_t)128*PADE_MAX + (unsigned)(slotB + ln*8)] = u;
    }

    // whole-wave early exit: no real slot in this 16-slot tile
    if (__ballot(ln < 16 && wval >= 0.f) == 0ull) return;

    float wrow = __shfl(wval, l16, 64);
    bool pad = (wrow < 0.f);

    float4v acc[8];
    #pragma unroll
    for (int n = 0; n < 8; n++) acc[n] = (float4v){0.f,0.f,0.f,0.f};

    #pragma unroll
    for (int s2 = 0; s2 < 4; s2++) {
        int kb = s2*32 + lh*8;
        float4 w1a = *(const float4*)&w1[kb];
        float4 w1b = *(const float4*)&w1[kb+4];
        float4 b1a = *(const float4*)&b1[kb];
        float4 b1b = *(const float4*)&b1[kb+4];
        float z0 = fmaxf(wrow*w1a.x + b1a.x, 0.f);
        float z1 = fmaxf(wrow*w1a.y + b1a.y, 0.f);
        float z2 = fmaxf(wrow*w1a.z + b1a.z, 0.f);
        float z3 = fmaxf(wrow*w1a.w + b1a.w, 0.f);
        float z4 = fmaxf(wrow*w1b.x + b1b.x, 0.f);
        float z5 = fmaxf(wrow*w1b.y + b1b.y, 0.f);
        float z6 = fmaxf(wrow*w1b.z + b1b.z, 0.f);
        float z7 = fmaxf(wrow*w1b.w + b1b.w, 0.f);
        uint4 ua;
        ua.x = pad ? 0u : pk_bf16(z0, z1);
        ua.y = pad ? 0u : pk_bf16(z2, z3);
        ua.z = pad ? 0u : pk_bf16(z4, z5);
        ua.w = pad ? 0u : pk_bf16(z6, z7);
        short8v a = *(short8v*)&ua;
        #pragma unroll
        for (int n = 0; n < 8; n++) {
            short8v b = *(const short8v*)&W2p[(size_t)((s2*8 + n)*64 + ln)*8];
            acc[n] = __builtin_amdgcn_mfma_f32_16x16x32_bf16(a, b, acc[n], 0, 0, 0);
        }
    }

    float wfl0 = __shfl(wval, 4*lh + 0, 64);
    float wfl1 = __shfl(wval, 4*lh + 1, 64);
    float wfl2 = __shfl(wval, 4*lh + 2, 64);
    float wfl3 = __shfl(wval, 4*lh + 3, 64);
    bool anyreal = (wfl0 >= 0.f) || (wfl1 >= 0.f) || (wfl2 >= 0.f) || (wfl3 >= 0.f);
    if (anyreal) {
        #pragma unroll
        for (int n = 0; n < 8; n++) {
            int col = 16*n + l16;
            float bb = b2[col];
            float v0 = (wfl0 < 0.f) ? 0.f : fmaxf(acc[n][0] + bb, 0.f);
            float v1 = (wfl1 < 0.f) ? 0.f : fmaxf(acc[n][1] + bb, 0.f);
            float v2 = (wfl2 < 0.f) ? 0.f : fmaxf(acc[n][2] + bb, 0.f);
            float v3 = (wfl3 < 0.f) ? 0.f : fmaxf(acc[n][3] + bb, 0.f);
            uint2 o = make_uint2(pk_bf16(v0, v1), pk_bf16(v2, v3));
            *(uint2*)&z2T[(size_t)col*PADE_MAX + (unsigned)(slotW + 4*lh)] = o;
        }
    }
}

// ---------------- BN column stats ----------------
__global__ __launch_bounds__(256) void k_bnstats(const float* __restrict__ h, float* __restrict__ stats)
{
    int t = threadIdx.x;
    float s = 0.f, ss = 0.f;
    for (size_t i = (size_t)blockIdx.x*256 + t; i < (size_t)NNODE*DD; i += (size_t)gridDim.x*256) {
        float v = h[i]; s += v; ss += v*v;
    }
    __shared__ float r0[256], r1[256];
    r0[t] = s; r1[t] = ss;
    __syncthreads();
    if (t < 32) {
        float a = 0.f, b = 0.f;
        for (int k = t; k < 256; k += 32) { a += r0[k]; b += r1[k]; }
        atomicAdd(&stats[t], a);
        atomicAdd(&stats[32 + t], b);
    }
}

// ---------------- gather BN(h) into transposed padded layout: hnT[d][padslot] ----------------
__global__ __launch_bounds__(256) void k_hgather(
    const float* __restrict__ hn, const int* __restrict__ sN, const int* __restrict__ padOff,
    const float* __restrict__ stats,
    const float* __restrict__ bng, const float* __restrict__ bnb,
    ushortT* __restrict__ hnT)
{
    int t = threadIdx.x;
    int slotB = blockIdx.x * 128;
    if (slotB >= padOff[NNODE]) return;
    int d = t >> 3;
    int sb = slotB + (t & 7) * 16;
    float mu  = stats[d] * (1.0f/(float)NNODE);
    float var = stats[DD+d] * (1.0f/(float)NNODE) - mu*mu;
    float sc = rsqrtf(var + 1e-5f) * bng[d];
    float sh = bnb[d] - mu*sc;
    float v[16];
    #pragma unroll
    for (int i = 0; i < 16; i++) {
        int n = sN[sb + i];
        v[i] = (n >= 0) ? (hn[(size_t)n*DD + d]*sc + sh) : 0.f;
    }
    uint4 o0, o1;
    o0.x = pk_bf16(v[0], v[1]);  o0.y = pk_bf16(v[2], v[3]);
    o0.z = pk_bf16(v[4], v[5]);  o0.w = pk_bf16(v[6], v[7]);
    o1.x = pk_bf16(v[8], v[9]);  o1.y = pk_bf16(v[10], v[11]);
    o1.z = pk_bf16(v[12], v[13]);o1.w = pk_bf16(v[14], v[15]);
    *(uint4*)&hnT[(size_t)d*PADE_MAX + sb]     = o0;
    *(uint4*)&hnT[(size_t)d*PADE_MAX + sb + 8] = o1;
}

// ---------------- fused NNConv, both phases MFMA ----------------
__global__ __launch_bounds__(256, 3) void k_conv(
    const float* __restrict__ hin, float* __restrict__ hout,
    const ushortT* __restrict__ z2T, const ushortT* __restrict__ hnT,
    const int* __restrict__ padOff, const int* __restrict__ deg,
    const ushortT* __restrict__ Bp, const float* __restrict__ convb)
{
    __shared__ ushortT sG[4][4128];      // 33 KB
    __shared__ float sred[4][4][DD];     // 2 KB

    int t = threadIdx.x, wv = t >> 6, ln = t & 63;
    int l16 = ln & 15, lh = ln >> 4;
    int c = blockIdx.x*4 + wv;
    int ks0 = padOff[c], ks1 = padOff[c+1];
    float idc = 1.f / fmaxf((float)deg[c], 1.f);

    float4v acc[9][2];
    #pragma unroll
    for (int m = 0; m < 9; m++) { acc[m][0] = (float4v){0,0,0,0}; acc[m][1] = (float4v){0,0,0,0}; }

    for (int ks = ks0; ks < ks1; ks += 32) {
        size_t kcol = (size_t)(ks + lh*8);
        short8v b0 = *(const short8v*)&hnT[(size_t)l16*PADE_MAX + kcol];
        short8v b1 = *(const short8v*)&hnT[(size_t)(16 + l16)*PADE_MAX + kcol];
        short8v a[9];
        #pragma unroll
        for (int m = 0; m < 9; m++)
            a[m] = *(const short8v*)&z2T[(size_t)(16*m + l16)*PADE_MAX + kcol];
        #pragma unroll
        for (int m = 0; m < 9; m++) {
            acc[m][0] = __builtin_amdgcn_mfma_f32_16x16x32_bf16(a[m], b0, acc[m][0], 0, 0, 0);
            acc[m][1] = __builtin_amdgcn_mfma_f32_16x16x32_bf16(a[m], b1, acc[m][1], 0, 0, 0);
        }
    }

    char* sGw = (char*)&sG[wv][0];
    #pragma unroll
    for (int m = 0; m < 9; m++) {
        #pragma unroll
        for (int r = 0; r < 4; r++) {
            int h = 16*m + 4*lh + r;
            bool live = (m < 8) || (lh == 0 && r == 0);   // h<=128
            if (live) {
                unsigned sw = (unsigned)(((h >> 2) & 3) << 4);
                #pragma unroll
                for (int n = 0; n < 2; n++) {
                    int d = 16*n + l16;
                    unsigned byte = (unsigned)(h*64) + (((unsigned)(d*2)) ^ sw);
                    *(ushortT*)(sGw + byte) = bf16s(acc[m][n][r] * idc);
                }
            }
        }
    }
    __syncthreads();

    float4v c0 = (float4v){0,0,0,0}, c1 = (float4v){0,0,0,0};
    for (int s = wv; s < NSTEP; s += 4) {
        short8v a = (short8v){0,0,0,0,0,0,0,0};
        if (l16 < 4) {
            unsigned sw = (unsigned)(((s >> 2) & 3) << 4);
            unsigned byte = (unsigned)(s*64) + (((unsigned)(lh*16)) ^ sw);
            a = *(const short8v*)((const char*)&sG[l16][0] + byte);
        }
        short8v b0 = *(const short8v*)&Bp[((size_t)s*2 + 0)*512 + ln*8];
        short8v b1 = *(const short8v*)&Bp[((size_t)s*2 + 1)*512 + ln*8];
        c0 = __builtin_amdgcn_mfma_f32_16x16x32_bf16(a, b0, c0, 0, 0, 0);
        c1 = __builtin_amdgcn_mfma_f32_16x16x32_bf16(a, b1, c1, 0, 0, 0);
    }
    if (lh == 0) {
        #pragma unroll
        for (int r = 0; r < 4; r++) {
            sred[wv][r][l16]      = c0[r];
            sred[wv][r][16 + l16] = c1[r];
        }
    }
    __syncthreads();

    if (t < 4*DD) {
        int cc = t >> 5, f = t & 31;
        float s = sred[0][cc][f] + sred[1][cc][f] + sred[2][cc][f] + sred[3][cc][f];
        int node = blockIdx.x*4 + cc;
        hout[(size_t)node*DD + f] = s + convb[f] + hin[(size_t)node*DD + f];
    }
}

// ---------------- LayerNorm into hLN ----------------
__global__ __launch_bounds__(256) void k_ln(const float* __restrict__ h,
    const float* __restrict__ lng, const float* __restrict__ lnb, float* __restrict__ hLN)
{
    int i = blockIdx.x * 256 + threadIdx.x;
    if (i >= NNODE) return;
    const float4* hr = (const float4*)(h + (size_t)i*DD);
    float4 v[8];
    float mu = 0.f;
    #pragma unroll
    for (int q = 0; q < 8; q++) { v[q] = hr[q]; mu += v[q].x+v[q].y+v[q].z+v[q].w; }
    mu *= (1.f/32.f);
    float var = 0.f;
    #pragma unroll
    for (int q = 0; q < 8; q++) {
        float d0=v[q].x-mu, d1=v[q].y-mu, d2=v[q].z-mu, d3=v[q].w-mu;
        var += d0*d0 + d1*d1 + d2*d2 + d3*d3;
    }
    var *= (1.f/32.f);
    float rs = rsqrtf(var + 1e-5f);
    float4* o = (float4*)(hLN + (size_t)i*DD);
    #pragma unroll
    for (int q = 0; q < 8; q++) {
        float4 gq = ((const float4*)lng)[q];
        float4 bq = ((const float4*)lnb)[q];
        float4 r;
        r.x = (v[q].x-mu)*rs*gq.x + bq.x;
        r.y = (v[q].y-mu)*rs*gq.y + bq.y;
        r.z = (v[q].z-mu)*rs*gq.z + bq.z;
        r.w = (v[q].w-mu)*rs*gq.w + bq.w;
        o[q] = r;
    }
}

// ---------------- fc1 partial GEMV: 86 K-slices x 32 graphs ----------------
__global__ __launch_bounds__(256) void k_fc1(const float* __restrict__ hLN,
    const float* __restrict__ w1, float* __restrict__ partial)
{
    int g = blockIdx.x / FC1S, s = blockIdx.x % FC1S;
    int j = threadIdx.x & 127, half = threadIdx.x >> 7;
    int k0 = s*96 + half*4;
    const float* x = hLN + (size_t)g*KPG;
    float a = 0.f;
    #pragma unroll
    for (int m = 0; m < 12; m++) {
        int k = k0 + m*8;
        float4 xv = *(const float4*)&x[k];
        const float* wp = w1 + (size_t)k*HIDN + j;
        a += xv.x * wp[0];
        a += xv.y * wp[HIDN];
        a += xv.z * wp[2*HIDN];
        a += xv.w * wp[3*HIDN];
    }
    partial[((size_t)blockIdx.x*2 + half)*HIDN + j] = a;
}

// ---------------- fc2: reduce 172 partials, lrelu, final GEMV ----------------
__global__ __launch_bounds__(128) void k_fc2(const float* __restrict__ partial,
    const float* __restrict__ b1, const float* __restrict__ w2,
    const float* __restrict__ b2, float* __restrict__ out)
{
    __shared__ float hid[128];
    int g = blockIdx.x, t = threadIdx.x;
    float a = b1[t];
    #pragma unroll 4
    for (int p = 0; p < 2*FC1S; p++) a += partial[(size_t)(g*2*FC1S + p)*HIDN + t];
    a = a >= 0.f ? a : 0.2f*a;
    hid[t] = a;
    __syncthreads();
    float o = b2[t];
    #pragma unroll 4
    for (int j = 0; j < 128; j++) o += hid[j]*w2[j*128 + t];
    out[(size_t)g*128 + t] = o;
}

extern "C" void kernel_launch(void* const* d_in, const int* in_sizes, int n_in,
                              void* d_out, int out_size, void* d_ws, size_t ws_size,
                              hipStream_t stream)
{
    const float* pos  = (const float*)d_in[0];
    const float* vel  = (const float*)d_in[1];
    const int*   eidx = (const int*)  d_in[2];
    const float* nw1 = (const float*)d_in[3];  const float* nb1 = (const float*)d_in[4];
    const float* nw2 = (const float*)d_in[5];  const float* nb2 = (const float*)d_in[6];
    const float* vw1 = (const float*)d_in[7];  const float* vb1 = (const float*)d_in[8];
    const float* vw2 = (const float*)d_in[9];  const float* vb2 = (const float*)d_in[10];
    const float* ew1 = (const float*)d_in[11]; const float* eb1 = (const float*)d_in[12];
    const float* ew2 = (const float*)d_in[13]; const float* eb2 = (const float*)d_in[14];
    const float* ew3 = (const float*)d_in[15]; const float* eb3 = (const float*)d_in[16];
    const float* cvb = (const float*)d_in[17];
    const float* b1g = (const float*)d_in[18]; const float* b1b = (const float*)d_in[19];
    const float* b2g = (const float*)d_in[20]; const float* b2b = (const float*)d_in[21];
    const float* lng = (const float*)d_in[22]; const float* lnb = (const float*)d_in[23];
    const float* fw1 = (const float*)d_in[24]; const float* fb1 = (const float*)d_in[25];
    const float* fw2 = (const float*)d_in[26]; const float* fb2 = (const float*)d_in[27];

    char* ws = (char*)d_ws;
    size_t off = 0;
    auto alloc = [&](size_t bytes) -> void* {
        void* p = ws + off;
        off = (off + bytes + 255) & ~(size_t)255;
        return p;
    };
    unsigned* maxd  = (unsigned*)alloc(4);
    float* stats1   = (float*)alloc(64*4);
    float* stats2   = (float*)alloc(64*4);
    int* deg        = (int*)alloc((size_t)NNODE*4);
    int* cursor     = (int*)alloc((size_t)NNODE*4);
    size_t zeroBytes = off;
    int* padOff     = (int*)alloc((size_t)(NNODE+1)*4);
    int* sN         = (int*)alloc((size_t)PADE_MAX*4);
    int* sE         = (int*)alloc((size_t)PADE_MAX*4);
    float* dist     = (float*)alloc((size_t)NEDGE*4);
    float* hA       = (float*)alloc((size_t)NNODE*DD*4);
    float* hB       = (float*)alloc((size_t)NNODE*DD*4);
    float* hLN      = (float*)alloc((size_t)NNODE*DD*4);
    float* partial  = (float*)alloc((size_t)NGR*2*FC1S*HIDN*4);
    ushortT* Bp     = (ushortT*)alloc((size_t)NSTEP*2*64*8*2);  // 264 KB
    ushortT* W2p    = (ushortT*)alloc((size_t)4*8*64*8*2);      // 32 KB
    ushortT* z2T    = (ushortT*)alloc((size_t)129*PADE_MAX*2);  // 85.2 MB
    ushortT* hnT    = (ushortT*)alloc((size_t)32*PADE_MAX*2);   // 21.1 MB

    hipMemsetAsync(d_ws, 0, zeroBytes, stream);
    hipMemsetAsync(sN, 0xFF, (size_t)PADE_MAX*4, stream);
    hipMemsetAsync(sE, 0xFF, (size_t)PADE_MAX*4, stream);

    k_encode<<<NNODE/32, 256, 0, stream>>>(pos, vel, nw1, nb1, nw2, nb2,
                                           vw1, vb1, vw2, vb2, hA);
    k_edge1<<<NEDGE/256, 256, 0, stream>>>(pos, eidx, dist, maxd, deg);
    k_scan<<<1, 1024, 0, stream>>>(deg, padOff);
    k_scatter<<<NEDGE/256, 256, 0, stream>>>(eidx, padOff, cursor, sN, sE);
    k_packB<<<(NSTEP*2*64 + 255)/256, 256, 0, stream>>>(ew3, eb3, Bp);
    k_packW2<<<8, 256, 0, stream>>>(ew2, W2p);
    k_z2<<<PADE_MAX/64, 256, 0, stream>>>(dist, maxd, sE, padOff,
                                          ew1, eb1, W2p, eb2, z2T);

    k_bnstats<<<64, 256, 0, stream>>>(hA, stats1);
    k_hgather<<<PADE_MAX/128, 256, 0, stream>>>(hA, sN, padOff, stats1, b1g, b1b, hnT);
    k_conv<<<NNODE/4, 256, 0, stream>>>(hA, hB, z2T, hnT, padOff, deg, Bp, cvb);

    k_bnstats<<<64, 256, 0, stream>>>(hB, stats2);
    k_hgather<<<PADE_MAX/128, 256, 0, stream>>>(hB, sN, padOff, stats2, b2g, b2b, hnT);
    k_conv<<<NNODE/4, 256, 0, stream>>>(hB, hA, z2T, hnT, padOff, deg, Bp, cvb);

    k_ln<<<(NNODE+255)/256, 256, 0, stream>>>(hA, lng, lnb, hLN);
    k_fc1<<<NGR*FC1S, 256, 0, stream>>>(hLN, fw1, partial);
    k_fc2<<<NGR, 128, 0, stream>>>(partial, fb1, fw2, fb2, (float*)d_out);
}

// Round 11
// 381.583 us; speedup vs baseline: 3.3121x; 1.0715x over previous
//
#include <hip/hip_runtime.h>
#include <hip/hip_bf16.h>

#define NNODE 8256
#define NEDGE 132096
#define DD 32
#define HIDN 128
#define NGR 32
#define PERG 258
#define KPG (PERG*DD)      // 8256
#define NSTEP 129          // phase-2 K-steps (128 h-rows + 1 bias row)
#define PADE_MAX 330240    // padded CSR capacity
#define FC1S 86            // fc1 K-slices (86*96 = 8256)

typedef unsigned short ushortT;
typedef __attribute__((ext_vector_type(8))) short short8v;   // 8 bf16
typedef __attribute__((ext_vector_type(4))) float float4v;   // MFMA 16x16 acc

__device__ __forceinline__ unsigned pk_bf16(float a, float b) {
    unsigned ua = __float_as_uint(a), ub = __float_as_uint(b);
    ua = (ua + 0x7fffu + ((ua >> 16) & 1u)) >> 16;
    ub = (ub + 0x7fffu + ((ub >> 16) & 1u)) >> 16;
    return ua | (ub << 16);
}
__device__ __forceinline__ ushortT bf16s(float a) {
    unsigned ua = __float_as_uint(a);
    return (ushortT)((ua + 0x7fffu + ((ua >> 16) & 1u)) >> 16);
}

// ---------------- node encoders + fused BN1 stats ----------------
__global__ __launch_bounds__(256) void k_encode(
    const float* __restrict__ pos, const float* __restrict__ vel,
    const float* __restrict__ nw1, const float* __restrict__ nb1,
    const float* __restrict__ nw2, const float* __restrict__ nb2,
    const float* __restrict__ vw1, const float* __restrict__ vb1,
    const float* __restrict__ vw2, const float* __restrict__ vb2,
    float* __restrict__ h, float* __restrict__ stats)
{
    __shared__ float s_nw1[384], s_nb1[128], s_nw2[2048];
    __shared__ float s_vw1[384], s_vb1[128], s_vw2[2048];
    __shared__ float s_nb2[16], s_vb2[16];
    __shared__ float s_rows[32][33];
    int t = threadIdx.x;
    for (int i = t; i < 384;  i += 256) { s_nw1[i] = nw1[i]; s_vw1[i] = vw1[i]; }
    for (int i = t; i < 128;  i += 256) { s_nb1[i] = nb1[i]; s_vb1[i] = vb1[i]; }
    for (int i = t; i < 2048; i += 256) { s_nw2[i] = nw2[i]; s_vw2[i] = vw2[i]; }
    if (t < 16) { s_nb2[t] = nb2[t]; s_vb2[t] = vb2[t]; }
    __syncthreads();

    int n = blockIdx.x * 32 + (t >> 3);
    int q = t & 7;
    float p0 = pos[n*3], p1 = pos[n*3+1], p2 = pos[n*3+2];
    float v0 = vel[n*3], v1 = vel[n*3+1], v2 = vel[n*3+2];
    float accP[16], accV[16];
    #pragma unroll
    for (int f = 0; f < 16; f++) { accP[f] = 0.f; accV[f] = 0.f; }
    int j0 = q * 16;
    #pragma unroll
    for (int jj = 0; jj < 16; jj++) {
        int j = j0 + jj;
        float hp = p0*s_nw1[j] + p1*s_nw1[128+j] + p2*s_nw1[256+j] + s_nb1[j];
        hp = hp >= 0.f ? hp : 0.2f*hp;
        float hv = v0*s_vw1[j] + v1*s_vw1[128+j] + v2*s_vw1[256+j] + s_vb1[j];
        hv = hv >= 0.f ? hv : 0.2f*hv;
        #pragma unroll
        for (int f = 0; f < 16; f++) {
            accP[f] += hp * s_nw2[j*16+f];
            accV[f] += hv * s_vw2[j*16+f];
        }
    }
    #pragma unroll
    for (int o = 1; o < 8; o <<= 1) {
        #pragma unroll
        for (int f = 0; f < 16; f++) {
            accP[f] += __shfl_xor(accP[f], o, 64);
            accV[f] += __shfl_xor(accV[f], o, 64);
        }
    }
    int nl = t >> 3;
    if (q == 0) {
        float4* op = (float4*)(h + (size_t)n*DD);
        #pragma unroll
        for (int m = 0; m < 4; m++) {
            float4 r = make_float4(accP[4*m]+s_nb2[4*m], accP[4*m+1]+s_nb2[4*m+1],
                                   accP[4*m+2]+s_nb2[4*m+2], accP[4*m+3]+s_nb2[4*m+3]);
            op[m] = r;
            s_rows[nl][4*m+0] = r.x; s_rows[nl][4*m+1] = r.y;
            s_rows[nl][4*m+2] = r.z; s_rows[nl][4*m+3] = r.w;
        }
        #pragma unroll
        for (int m = 0; m < 4; m++) {
            float4 r = make_float4(accV[4*m]+s_vb2[4*m], accV[4*m+1]+s_vb2[4*m+1],
                                   accV[4*m+2]+s_vb2[4*m+2], accV[4*m+3]+s_vb2[4*m+3]);
            op[4+m] = r;
            s_rows[nl][16+4*m+0] = r.x; s_rows[nl][16+4*m+1] = r.y;
            s_rows[nl][16+4*m+2] = r.z; s_rows[nl][16+4*m+3] = r.w;
        }
    }
    __syncthreads();
    if (t < 32) {
        float s = 0.f, ss = 0.f;
        #pragma unroll 8
        for (int r = 0; r < 32; r++) {
            float v = s_rows[r][t];
            s += v; ss += v*v;
        }
        atomicAdd(&stats[t], s);
        atomicAdd(&stats[32 + t], ss);
    }
}

// ---------------- per-edge dist, max-dist, degree count ----------------
__global__ __launch_bounds__(256) void k_edge1(
    const float* __restrict__ pos, const int* __restrict__ ei,
    float* __restrict__ dist, unsigned* __restrict__ maxd, int* __restrict__ deg)
{
    int e = blockIdx.x * 256 + threadIdx.x;
    float dd = 0.f;
    if (e < NEDGE) {
        int c = ei[e], n = ei[NEDGE + e];
        float dx = pos[c*3]   - pos[n*3];
        float dy = pos[c*3+1] - pos[n*3+1];
        float dz = pos[c*3+2] - pos[n*3+2];
        dd = sqrtf(dx*dx + dy*dy + dz*dz);
        dist[e] = dd;
        atomicAdd(&deg[c], 1);
    }
    #pragma unroll
    for (int o = 32; o > 0; o >>= 1) dd = fmaxf(dd, __shfl_down(dd, o, 64));
    if ((threadIdx.x & 63) == 0) atomicMax(maxd, __float_as_uint(dd));
}

// ---------------- exclusive scan of PADDED degrees ----------------
__global__ __launch_bounds__(1024) void k_scan(const int* __restrict__ deg, int* __restrict__ off)
{
    __shared__ int s[1024];
    int t = threadIdx.x;
    int base = t * 9;
    int loc[9]; int sum = 0;
    #pragma unroll
    for (int k = 0; k < 9; k++) {
        int i = base + k;
        int v = (i < NNODE) ? ((deg[i] + 31) & ~31) : 0;
        loc[k] = sum; sum += v;
    }
    s[t] = sum; __syncthreads();
    for (int o = 1; o < 1024; o <<= 1) {
        int v = (t >= o) ? s[t - o] : 0;
        __syncthreads();
        s[t] += v;
        __syncthreads();
    }
    int pre = (t == 0) ? 0 : s[t-1];
    #pragma unroll
    for (int k = 0; k < 9; k++) {
        int i = base + k;
        if (i < NNODE) off[i] = pre + loc[k];
    }
    if (t == 1023) off[NNODE] = s[1023];
}

// ---------------- scatter edges into padded CSR slots ----------------
__global__ __launch_bounds__(256) void k_scatter(
    const int* __restrict__ ei, const int* __restrict__ off,
    int* __restrict__ cursor, int* __restrict__ sN, int* __restrict__ sE)
{
    int e = blockIdx.x * 256 + threadIdx.x;
    if (e >= NEDGE) return;
    int c = ei[e];
    int p = off[c] + atomicAdd(&cursor[c], 1);
    sN[p] = ei[NEDGE + e];
    sE[p] = e;
}

// ---------------- pack B = [w3 ; b3] (MFMA frag order, bf16) ----------------
__global__ __launch_bounds__(256) void k_packB(
    const float* __restrict__ w3, const float* __restrict__ b3, ushortT* __restrict__ Bp)
{
    int gid = blockIdx.x*256 + threadIdx.x;
    if (gid >= NSTEP*2*64) return;
    int step = gid >> 7;
    int ntile = (gid >> 6) & 1;
    int lane = gid & 63;
    int col = ntile*16 + (lane & 15);
    int kb = step*32 + 8*(lane >> 4);
    float v[8];
    #pragma unroll
    for (int j = 0; j < 8; j++) {
        int k = kb + j;
        v[j] = (k < 4096) ? w3[(size_t)k*DD + col] : b3[(size_t)(k - 4096)*DD + col];
    }
    uint4 o;
    o.x = pk_bf16(v[0], v[1]);
    o.y = pk_bf16(v[2], v[3]);
    o.z = pk_bf16(v[4], v[5]);
    o.w = pk_bf16(v[6], v[7]);
    *(uint4*)&Bp[(size_t)gid*8] = o;
}

// ---------------- pack W2 (MFMA frag order, bf16) ----------------
__global__ __launch_bounds__(256) void k_packW2(
    const float* __restrict__ w2, ushortT* __restrict__ W2p)
{
    int gid = blockIdx.x*256 + threadIdx.x;
    if (gid >= 4*8*64) return;
    int s2 = gid >> 9;
    int n  = (gid >> 6) & 7;
    int lane = gid & 63;
    int col = 16*n + (lane & 15);
    int kb = 32*s2 + 8*(lane >> 4);
    float v[8];
    #pragma unroll
    for (int j = 0; j < 8; j++) v[j] = w2[(size_t)(kb + j)*HIDN + col];
    uint4 o;
    o.x = pk_bf16(v[0], v[1]);
    o.y = pk_bf16(v[2], v[3]);
    o.z = pk_bf16(v[4], v[5]);
    o.w = pk_bf16(v[6], v[7]);
    *(uint4*)&W2p[(size_t)gid*8] = o;
}

// ---------------- z2 via MFMA (W2p staged in LDS), transposed out; pad-skip ----------------
__global__ __launch_bounds__(256, 4) void k_z2(
    const float* __restrict__ dist, const unsigned* __restrict__ maxdb,
    const int* __restrict__ sE, const int* __restrict__ padOff,
    const float* __restrict__ w1, const float* __restrict__ b1,
    const ushortT* __restrict__ W2p, const float* __restrict__ b2,
    ushortT* __restrict__ z2T)
{
    __shared__ __align__(16) ushortT sW2[16384];   // 32 KB = 2048 uint4
    int t = threadIdx.x, wv = t >> 6, ln = t & 63;
    int slotB = blockIdx.x * 64;
    int padE = padOff[NNODE];
    if (slotB >= padE) return;

    {
        const uint4* src = (const uint4*)W2p;
        uint4* dst = (uint4*)sW2;
        #pragma unroll
        for (int i = 0; i < 8; i++) dst[t + i*256] = src[t + i*256];   // FIX: 8*256 = 2048 uint4
    }
    __syncthreads();

    int slotW = slotB + wv*16;
    int l16 = ln & 15, lh = ln >> 4;

    float wval = -1.f;
    if (ln < 16) {
        int e = sE[slotW + ln];
        if (e >= 0) {
            float inv = 3.14159265358979323846f / __uint_as_float(*maxdb);
            wval = 0.5f * (cosf(dist[e] * inv) + 1.0f);
        }
    }

    if (wv == 0 && ln < 8) {
        uint4 u = make_uint4(0x3F803F80u, 0x3F803F80u, 0x3F803F80u, 0x3F803F80u);
        *(uint4*)&z2T[(size_t)128*PADE_MAX + (unsigned)(slotB + ln*8)] = u;
    }

    if (__ballot(ln < 16 && wval >= 0.f) == 0ull) return;

    float wrow = __shfl(wval, l16, 64);
    bool pad = (wrow < 0.f);

    float4v acc[8];
    #pragma unroll
    for (int n = 0; n < 8; n++) acc[n] = (float4v){0.f,0.f,0.f,0.f};

    #pragma unroll
    for (int s2 = 0; s2 < 4; s2++) {
        int kb = s2*32 + lh*8;
        float4 w1a = *(const float4*)&w1[kb];
        float4 w1b = *(const float4*)&w1[kb+4];
        float4 b1a = *(const float4*)&b1[kb];
        float4 b1b = *(const float4*)&b1[kb+4];
        float z0 = fmaxf(wrow*w1a.x + b1a.x, 0.f);
        float z1 = fmaxf(wrow*w1a.y + b1a.y, 0.f);
        float z2 = fmaxf(wrow*w1a.z + b1a.z, 0.f);
        float z3 = fmaxf(wrow*w1a.w + b1a.w, 0.f);
        float z4 = fmaxf(wrow*w1b.x + b1b.x, 0.f);
        float z5 = fmaxf(wrow*w1b.y + b1b.y, 0.f);
        float z6 = fmaxf(wrow*w1b.z + b1b.z, 0.f);
        float z7 = fmaxf(wrow*w1b.w + b1b.w, 0.f);
        uint4 ua;
        ua.x = pad ? 0u : pk_bf16(z0, z1);
        ua.y = pad ? 0u : pk_bf16(z2, z3);
        ua.z = pad ? 0u : pk_bf16(z4, z5);
        ua.w = pad ? 0u : pk_bf16(z6, z7);
        short8v a = *(short8v*)&ua;
        #pragma unroll
        for (int n = 0; n < 8; n++) {
            short8v b = *(const short8v*)&sW2[(size_t)((s2*8 + n)*64 + ln)*8];
            acc[n] = __builtin_amdgcn_mfma_f32_16x16x32_bf16(a, b, acc[n], 0, 0, 0);
        }
    }

    float wfl0 = __shfl(wval, 4*lh + 0, 64);
    float wfl1 = __shfl(wval, 4*lh + 1, 64);
    float wfl2 = __shfl(wval, 4*lh + 2, 64);
    float wfl3 = __shfl(wval, 4*lh + 3, 64);
    bool anyreal = (wfl0 >= 0.f) || (wfl1 >= 0.f) || (wfl2 >= 0.f) || (wfl3 >= 0.f);
    if (anyreal) {
        #pragma unroll
        for (int n = 0; n < 8; n++) {
            int col = 16*n + l16;
            float bb = b2[col];
            float v0 = (wfl0 < 0.f) ? 0.f : fmaxf(acc[n][0] + bb, 0.f);
            float v1 = (wfl1 < 0.f) ? 0.f : fmaxf(acc[n][1] + bb, 0.f);
            float v2 = (wfl2 < 0.f) ? 0.f : fmaxf(acc[n][2] + bb, 0.f);
            float v3 = (wfl3 < 0.f) ? 0.f : fmaxf(acc[n][3] + bb, 0.f);
            uint2 o = make_uint2(pk_bf16(v0, v1), pk_bf16(v2, v3));
            *(uint2*)&z2T[(size_t)col*PADE_MAX + (unsigned)(slotW + 4*lh)] = o;
        }
    }
}

// ---------------- gather BN(h) -> hnT[d][padslot], coalesced via LDS transpose ----------------
__global__ __launch_bounds__(256) void k_hgather(
    const float* __restrict__ hn, const int* __restrict__ sN, const int* __restrict__ padOff,
    const float* __restrict__ stats,
    const float* __restrict__ bng, const float* __restrict__ bnb,
    ushortT* __restrict__ hnT)
{
    __shared__ float s_scale[DD], s_shift[DD];
    __shared__ ushortT sT[DD][66];
    int t = threadIdx.x;
    if (t < DD) {
        float mu  = stats[t] * (1.0f/(float)NNODE);
        float var = stats[DD+t] * (1.0f/(float)NNODE) - mu*mu;
        float sc = rsqrtf(var + 1e-5f) * bng[t];
        s_scale[t] = sc;
        s_shift[t] = bnb[t] - mu*sc;
    }
    __syncthreads();
    int slotB = blockIdx.x * 64;
    if (slotB >= padOff[NNODE]) return;
    int sl = t >> 2, q = t & 3;
    int n = sN[slotB + sl];
    float v[8];
    if (n >= 0) {
        const float* hr = hn + (size_t)n*DD + q*8;
        float4 x0 = *(const float4*)hr;
        float4 x1 = *(const float4*)(hr + 4);
        int c0 = q*8;
        v[0] = x0.x*s_scale[c0+0] + s_shift[c0+0];
        v[1] = x0.y*s_scale[c0+1] + s_shift[c0+1];
        v[2] = x0.z*s_scale[c0+2] + s_shift[c0+2];
        v[3] = x0.w*s_scale[c0+3] + s_shift[c0+3];
        v[4] = x1.x*s_scale[c0+4] + s_shift[c0+4];
        v[5] = x1.y*s_scale[c0+5] + s_shift[c0+5];
        v[6] = x1.z*s_scale[c0+6] + s_shift[c0+6];
        v[7] = x1.w*s_scale[c0+7] + s_shift[c0+7];
    } else {
        #pragma unroll
        for (int j = 0; j < 8; j++) v[j] = 0.f;
    }
    #pragma unroll
    for (int j = 0; j < 8; j++) sT[q*8 + j][sl] = bf16s(v[j]);
    __syncthreads();
    int d = t >> 3, p = t & 7;
    unsigned w0 = (unsigned)sT[d][p*8+0] | ((unsigned)sT[d][p*8+1] << 16);
    unsigned w1 = (unsigned)sT[d][p*8+2] | ((unsigned)sT[d][p*8+3] << 16);
    unsigned w2 = (unsigned)sT[d][p*8+4] | ((unsigned)sT[d][p*8+5] << 16);
    unsigned w3 = (unsigned)sT[d][p*8+6] | ((unsigned)sT[d][p*8+7] << 16);
    *(uint4*)&hnT[(size_t)d*PADE_MAX + slotB + p*8] = make_uint4(w0, w1, w2, w3);
}

// ---------------- fused NNConv (MFMA both phases) + optional stats/LN epilogue ----------------
__global__ __launch_bounds__(256, 3) void k_conv(
    const float* __restrict__ hin, float* __restrict__ hout,
    const ushortT* __restrict__ z2T, const ushortT* __restrict__ hnT,
    const int* __restrict__ padOff, const int* __restrict__ deg,
    const ushortT* __restrict__ Bp, const float* __restrict__ convb,
    float* __restrict__ statsOut,
    const float* __restrict__ lng, const float* __restrict__ lnb,
    float* __restrict__ hLNout)
{
    __shared__ ushortT sG[4][4128];      // 33 KB
    __shared__ float sred[4][4][DD];
    __shared__ float s_stat[64];

    int t = threadIdx.x, wv = t >> 6, ln = t & 63;
    int l16 = ln & 15, lh = ln >> 4;
    if (t < 64) s_stat[t] = 0.f;
    int c = blockIdx.x*4 + wv;
    int ks0 = padOff[c], ks1 = padOff[c+1];
    float idc = 1.f / fmaxf((float)deg[c], 1.f);

    float4v acc[9][2];
    #pragma unroll
    for (int m = 0; m < 9; m++) { acc[m][0] = (float4v){0,0,0,0}; acc[m][1] = (float4v){0,0,0,0}; }

    for (int ks = ks0; ks < ks1; ks += 32) {
        size_t kcol = (size_t)(ks + lh*8);
        short8v b0 = *(const short8v*)&hnT[(size_t)l16*PADE_MAX + kcol];
        short8v b1 = *(const short8v*)&hnT[(size_t)(16 + l16)*PADE_MAX + kcol];
        short8v a[9];
        #pragma unroll
        for (int m = 0; m < 9; m++)
            a[m] = *(const short8v*)&z2T[(size_t)(16*m + l16)*PADE_MAX + kcol];
        #pragma unroll
        for (int m = 0; m < 9; m++) {
            acc[m][0] = __builtin_amdgcn_mfma_f32_16x16x32_bf16(a[m], b0, acc[m][0], 0, 0, 0);
            acc[m][1] = __builtin_amdgcn_mfma_f32_16x16x32_bf16(a[m], b1, acc[m][1], 0, 0, 0);
        }
    }

    char* sGw = (char*)&sG[wv][0];
    #pragma unroll
    for (int m = 0; m < 9; m++) {
        #pragma unroll
        for (int r = 0; r < 4; r++) {
            int h = 16*m + 4*lh + r;
            bool live = (m < 8) || (lh == 0 && r == 0);
            if (live) {
                unsigned sw = (unsigned)(((h >> 2) & 3) << 4);
                #pragma unroll
                for (int n = 0; n < 2; n++) {
                    int d = 16*n + l16;
                    unsigned byte = (unsigned)(h*64) + (((unsigned)(d*2)) ^ sw);
                    *(ushortT*)(sGw + byte) = bf16s(acc[m][n][r] * idc);
                }
            }
        }
    }
    __syncthreads();

    // phase 2: unroll x2, dual accumulators, unconditional sG reads (l16&3)
    const char* sGb = (const char*)&sG[l16 & 3][0];
    float4v c0 = (float4v){0,0,0,0}, c1 = (float4v){0,0,0,0};
    float4v d0 = (float4v){0,0,0,0}, d1 = (float4v){0,0,0,0};
    int s = wv;
    for (; s + 4 < NSTEP; s += 8) {
        int s2 = s + 4;
        unsigned byA = (unsigned)(s*64)  + (((unsigned)(lh*16)) ^ (unsigned)(((s  >> 2) & 3) << 4));
        unsigned byB = (unsigned)(s2*64) + (((unsigned)(lh*16)) ^ (unsigned)(((s2 >> 2) & 3) << 4));
        short8v aA = *(const short8v*)(sGb + byA);
        short8v aB = *(const short8v*)(sGb + byB);
        short8v b0A = *(const short8v*)&Bp[((size_t)s*2  + 0)*512 + ln*8];
        short8v b1A = *(const short8v*)&Bp[((size_t)s*2  + 1)*512 + ln*8];
        short8v b0B = *(const short8v*)&Bp[((size_t)s2*2 + 0)*512 + ln*8];
        short8v b1B = *(const short8v*)&Bp[((size_t)s2*2 + 1)*512 + ln*8];
        c0 = __builtin_amdgcn_mfma_f32_16x16x32_bf16(aA, b0A, c0, 0, 0, 0);
        c1 = __builtin_amdgcn_mfma_f32_16x16x32_bf16(aA, b1A, c1, 0, 0, 0);
        d0 = __builtin_amdgcn_mfma_f32_16x16x32_bf16(aB, b0B, d0, 0, 0, 0);
        d1 = __builtin_amdgcn_mfma_f32_16x16x32_bf16(aB, b1B, d1, 0, 0, 0);
    }
    for (; s < NSTEP; s += 4) {
        unsigned byA = (unsigned)(s*64) + (((unsigned)(lh*16)) ^ (unsigned)(((s >> 2) & 3) << 4));
        short8v aA = *(const short8v*)(sGb + byA);
        short8v b0A = *(const short8v*)&Bp[((size_t)s*2 + 0)*512 + ln*8];
        short8v b1A = *(const short8v*)&Bp[((size_t)s*2 + 1)*512 + ln*8];
        c0 = __builtin_amdgcn_mfma_f32_16x16x32_bf16(aA, b0A, c0, 0, 0, 0);
        c1 = __builtin_amdgcn_mfma_f32_16x16x32_bf16(aA, b1A, c1, 0, 0, 0);
    }
    #pragma unroll
    for (int r = 0; r < 4; r++) { c0[r] += d0[r]; c1[r] += d1[r]; }

    if (lh == 0) {
        #pragma unroll
        for (int r = 0; r < 4; r++) {
            sred[wv][r][l16]      = c0[r];
            sred[wv][r][16 + l16] = c1[r];
        }
    }
    __syncthreads();

    if (t < 4*DD) {
        int cc = t >> 5, f = t & 31;
        float sv = sred[0][cc][f] + sred[1][cc][f] + sred[2][cc][f] + sred[3][cc][f];
        int node = blockIdx.x*4 + cc;
        sv += convb[f] + hin[(size_t)node*DD + f];
        hout[(size_t)node*DD + f] = sv;
        if (statsOut) {
            atomicAdd(&s_stat[f], sv);
            atomicAdd(&s_stat[32 + f], sv*sv);
        }
        if (hLNout) {
            float m1 = sv, m2 = sv*sv;
            #pragma unroll
            for (int o = 1; o < 32; o <<= 1) {
                m1 += __shfl_xor(m1, o, 32);
                m2 += __shfl_xor(m2, o, 32);
            }
            m1 *= (1.f/32.f);
            float var = m2*(1.f/32.f) - m1*m1;
            float rs = rsqrtf(var + 1e-5f);
            hLNout[(size_t)node*DD + f] = (sv - m1)*rs*lng[f] + lnb[f];
        }
    }
    if (statsOut) {
        __syncthreads();
        if (t < 64) atomicAdd(&statsOut[t], s_stat[t]);
    }
}

// ---------------- fc1 partial GEMV: 86 K-slices x 32 graphs ----------------
__global__ __launch_bounds__(256) void k_fc1(const float* __restrict__ hLN,
    const float* __restrict__ w1, float* __restrict__ partial)
{
    int g = blockIdx.x / FC1S, s = blockIdx.x % FC1S;
    int j = threadIdx.x & 127, half = threadIdx.x >> 7;
    int k0 = s*96 + half*4;
    const float* x = hLN + (size_t)g*KPG;
    float a = 0.f;
    #pragma unroll
    for (int m = 0; m < 12; m++) {
        int k = k0 + m*8;
        float4 xv = *(const float4*)&x[k];
        const float* wp = w1 + (size_t)k*HIDN + j;
        a += xv.x * wp[0];
        a += xv.y * wp[HIDN];
        a += xv.z * wp[2*HIDN];
        a += xv.w * wp[3*HIDN];
    }
    partial[((size_t)blockIdx.x*2 + half)*HIDN + j] = a;
}

// ---------------- fc2 ----------------
__global__ __launch_bounds__(128) void k_fc2(const float* __restrict__ partial,
    const float* __restrict__ b1, const float* __restrict__ w2,
    const float* __restrict__ b2, float* __restrict__ out)
{
    __shared__ float hid[128];
    int g = blockIdx.x, t = threadIdx.x;
    float a = b1[t];
    #pragma unroll 4
    for (int p = 0; p < 2*FC1S; p++) a += partial[(size_t)(g*2*FC1S + p)*HIDN + t];
    a = a >= 0.f ? a : 0.2f*a;
    hid[t] = a;
    __syncthreads();
    float o = b2[t];
    #pragma unroll 4
    for (int j = 0; j < 128; j++) o += hid[j]*w2[j*128 + t];
    out[(size_t)g*128 + t] = o;
}

extern "C" void kernel_launch(void* const* d_in, const int* in_sizes, int n_in,
                              void* d_out, int out_size, void* d_ws, size_t ws_size,
                              hipStream_t stream)
{
    const float* pos  = (const float*)d_in[0];
    const float* vel  = (const float*)d_in[1];
    const int*   eidx = (const int*)  d_in[2];
    const float* nw1 = (const float*)d_in[3];  const float* nb1 = (const float*)d_in[4];
    const float* nw2 = (const float*)d_in[5];  const float* nb2 = (const float*)d_in[6];
    const float* vw1 = (const float*)d_in[7];  const float* vb1 = (const float*)d_in[8];
    const float* vw2 = (const float*)d_in[9];  const float* vb2 = (const float*)d_in[10];
    const float* ew1 = (const float*)d_in[11]; const float* eb1 = (const float*)d_in[12];
    const float* ew2 = (const float*)d_in[13]; const float* eb2 = (const float*)d_in[14];
    const float* ew3 = (const float*)d_in[15]; const float* eb3 = (const float*)d_in[16];
    const float* cvb = (const float*)d_in[17];
    const float* b1g = (const float*)d_in[18]; const float* b1b = (const float*)d_in[19];
    const float* b2g = (const float*)d_in[20]; const float* b2b = (const float*)d_in[21];
    const float* lng = (const float*)d_in[22]; const float* lnb = (const float*)d_in[23];
    const float* fw1 = (const float*)d_in[24]; const float* fb1 = (const float*)d_in[25];
    const float* fw2 = (const float*)d_in[26]; const float* fb2 = (const float*)d_in[27];

    char* ws = (char*)d_ws;
    size_t off = 0;
    auto alloc = [&](size_t bytes) -> void* {
        void* p = ws + off;
        off = (off + bytes + 255) & ~(size_t)255;
        return p;
    };
    unsigned* maxd  = (unsigned*)alloc(4);
    float* stats1   = (float*)alloc(64*4);
    float* stats2   = (float*)alloc(64*4);
    int* deg        = (int*)alloc((size_t)NNODE*4);
    int* cursor     = (int*)alloc((size_t)NNODE*4);
    size_t zeroBytes = off;
    int* padOff     = (int*)alloc((size_t)(NNODE+1)*4);
    int* sN         = (int*)alloc((size_t)PADE_MAX*4);
    int* sE         = (int*)alloc((size_t)PADE_MAX*4);
    float* dist     = (float*)alloc((size_t)NEDGE*4);
    float* hA       = (float*)alloc((size_t)NNODE*DD*4);
    float* hB       = (float*)alloc((size_t)NNODE*DD*4);
    float* hLN      = (float*)alloc((size_t)NNODE*DD*4);
    float* partial  = (float*)alloc((size_t)NGR*2*FC1S*HIDN*4);
    ushortT* Bp     = (ushortT*)alloc((size_t)NSTEP*2*64*8*2);  // 264 KB
    ushortT* W2p    = (ushortT*)alloc((size_t)4*8*64*8*2);      // 32 KB
    ushortT* z2T    = (ushortT*)alloc((size_t)129*PADE_MAX*2);  // 85.2 MB
    ushortT* hnT    = (ushortT*)alloc((size_t)32*PADE_MAX*2);   // 21.1 MB

    hipMemsetAsync(d_ws, 0, zeroBytes, stream);
    hipMemsetAsync(sN, 0xFF, (size_t)PADE_MAX*4, stream);
    hipMemsetAsync(sE, 0xFF, (size_t)PADE_MAX*4, stream);

    k_encode<<<NNODE/32, 256, 0, stream>>>(pos, vel, nw1, nb1, nw2, nb2,
                                           vw1, vb1, vw2, vb2, hA, stats1);
    k_edge1<<<NEDGE/256, 256, 0, stream>>>(pos, eidx, dist, maxd, deg);
    k_scan<<<1, 1024, 0, stream>>>(deg, padOff);
    k_scatter<<<NEDGE/256, 256, 0, stream>>>(eidx, padOff, cursor, sN, sE);
    k_packB<<<(NSTEP*2*64 + 255)/256, 256, 0, stream>>>(ew3, eb3, Bp);
    k_packW2<<<8, 256, 0, stream>>>(ew2, W2p);
    k_z2<<<PADE_MAX/64, 256, 0, stream>>>(dist, maxd, sE, padOff,
                                          ew1, eb1, W2p, eb2, z2T);

    k_hgather<<<PADE_MAX/64, 256, 0, stream>>>(hA, sN, padOff, stats1, b1g, b1b, hnT);
    k_conv<<<NNODE/4, 256, 0, stream>>>(hA, hB, z2T, hnT, padOff, deg, Bp, cvb,
                                        stats2, nullptr, nullptr, nullptr);

    k_hgather<<<PADE_MAX/64, 256, 0, stream>>>(hB, sN, padOff, stats2, b2g, b2b, hnT);
    k_conv<<<NNODE/4, 256, 0, stream>>>(hB, hA, z2T, hnT, padOff, deg, Bp, cvb,
                                        nullptr, lng, lnb, hLN);

    k_fc1<<<NGR*FC1S, 256, 0, stream>>>(hLN, fw1, partial);
    k_fc2<<<NGR, 128, 0, stream>>>(partial, fb1, fw2, fb2, (float*)d_out);
}